// Round 9
// baseline (561.873 us; speedup 1.0000x reference)
//
#include <hip/hip_runtime.h>
#include <cmath>

#define B_ 4
#define S_ 1024
#define H_ 1024

typedef short bf16x8 __attribute__((ext_vector_type(8)));
typedef float f32x4 __attribute__((ext_vector_type(4)));
typedef _Float16 half4 __attribute__((ext_vector_type(4)));

__device__ __forceinline__ unsigned short f2bf(float f) {
  unsigned u = __float_as_uint(f);
  u += 0x7fff + ((u >> 16) & 1);  // RTNE
  return (unsigned short)(u >> 16);
}
__device__ __forceinline__ float bf2f(unsigned short h) {
  return __uint_as_float(((unsigned)h) << 16);
}
__device__ __forceinline__ void gld16(const void* g, void* l) {
  __builtin_amdgcn_global_load_lds(
      (const __attribute__((address_space(1))) unsigned int*)g,
      (__attribute__((address_space(3))) unsigned int*)l, 16, 0, 0);
}

// ---------------------------------------------------------------- gating ----
__global__ __launch_bounds__(64) void gate_kernel(
    const float* __restrict__ x, const float* __restrict__ Wg,
    float* __restrict__ gw) {
  int t = blockIdx.x;
  int lane = threadIdx.x;
  const float* xr = x + (size_t)t * H_;
  float a0 = 0.f, a1 = 0.f, a2 = 0.f, a3 = 0.f;
  for (int h = lane; h < H_; h += 64) {
    float xv = xr[h];
    const float* wr = Wg + h * 4;
    a0 += xv * wr[0]; a1 += xv * wr[1]; a2 += xv * wr[2]; a3 += xv * wr[3];
  }
  for (int off = 32; off > 0; off >>= 1) {
    a0 += __shfl_down(a0, off);
    a1 += __shfl_down(a1, off);
    a2 += __shfl_down(a2, off);
    a3 += __shfl_down(a3, off);
  }
  if (lane == 0) {
    float v[4] = {a0, a1, a2, a3};
    int i0 = 0; float b0 = v[0];
    for (int e = 1; e < 4; ++e) if (v[e] > b0) { b0 = v[e]; i0 = e; }
    int i1 = -1; float b1 = -INFINITY;
    for (int e = 0; e < 4; ++e) { if (e == i0) continue; if (v[e] > b1) { b1 = v[e]; i1 = e; } }
    float e1v = expf(b1 - b0);
    float w0 = 1.f / (1.f + e1v);
    float w1 = e1v / (1.f + e1v);
    float o[4] = {0.f, 0.f, 0.f, 0.f};
    o[i0] = w0; o[i1] = w1;
    float* g = gw + t * 4;
    g[0] = o[0]; g[1] = o[1]; g[2] = o[2]; g[3] = o[3];
  }
}

// ---------------- gating + fp32->bf16 conversion fused (same math/order) ----
__global__ __launch_bounds__(64) void gate_conv_kernel(
    const float* __restrict__ x, const float* __restrict__ Wg,
    float* __restrict__ gw, unsigned short* __restrict__ xb) {
  int t = blockIdx.x;
  int lane = threadIdx.x;
  const float* xr = x + (size_t)t * H_;
  unsigned short* xbr = xb + (size_t)t * H_;
  float a0 = 0.f, a1 = 0.f, a2 = 0.f, a3 = 0.f;
  for (int h = lane; h < H_; h += 64) {
    float xv = xr[h];
    xbr[h] = f2bf(xv);
    const float* wr = Wg + h * 4;
    a0 += xv * wr[0]; a1 += xv * wr[1]; a2 += xv * wr[2]; a3 += xv * wr[3];
  }
  for (int off = 32; off > 0; off >>= 1) {
    a0 += __shfl_down(a0, off);
    a1 += __shfl_down(a1, off);
    a2 += __shfl_down(a2, off);
    a3 += __shfl_down(a3, off);
  }
  if (lane == 0) {
    float v[4] = {a0, a1, a2, a3};
    int i0 = 0; float b0 = v[0];
    for (int e = 1; e < 4; ++e) if (v[e] > b0) { b0 = v[e]; i0 = e; }
    int i1 = -1; float b1 = -INFINITY;
    for (int e = 0; e < 4; ++e) { if (e == i0) continue; if (v[e] > b1) { b1 = v[e]; i1 = e; } }
    float e1v = expf(b1 - b0);
    float w0 = 1.f / (1.f + e1v);
    float w1 = e1v / (1.f + e1v);
    float o[4] = {0.f, 0.f, 0.f, 0.f};
    o[i0] = w0; o[i1] = w1;
    float* g = gw + t * 4;
    g[0] = o[0]; g[1] = o[1]; g[2] = o[2]; g[3] = o[3];
  }
}

// -------------------------------------------------------- fp32 -> bf16 ------
__global__ __launch_bounds__(256) void conv_kernel(
    const float* __restrict__ src, unsigned short* __restrict__ dst,
    int nsrc, int ldsrc) {
  int idx = blockIdx.x * 256 + threadIdx.x;
  int m = idx >> 10, c = idx & 1023;
  dst[idx] = (c < nsrc) ? f2bf(src[(size_t)m * ldsrc + c]) : (unsigned short)0;
}

// --------------------- weight transpose + bf16, 4 matrices in one launch ----
__global__ __launch_bounds__(256) void wtrans4_kernel(
    const float* __restrict__ s0, const float* __restrict__ s1,
    const float* __restrict__ s2, const float* __restrict__ s3,
    unsigned short* __restrict__ d0, unsigned short* __restrict__ d1,
    unsigned short* __restrict__ d2, unsigned short* __restrict__ d3, int pd) {
  __shared__ float tile[32][33];
  int z = blockIdx.z;
  const float* src = (z == 0) ? s0 : (z == 1) ? s1 : (z == 2) ? s2 : s3;
  unsigned short* dst = (z == 0) ? d0 : (z == 1) ? d1 : (z == 2) ? d2 : d3;
  int ksrc = (z < 3) ? 1024 : pd;
  int nsrc = (z < 3) ? pd : 1024;
  int ldsrc = (z < 3) ? pd : 1024;
  int k0 = blockIdx.x * 32, n0 = blockIdx.y * 32;
  int tx = threadIdx.x & 31, ty = threadIdx.x >> 5;
  for (int i = 0; i < 32; i += 8) {
    int k = k0 + ty + i, n = n0 + tx;
    tile[ty + i][tx] = (k < ksrc && n < nsrc) ? src[(size_t)k * ldsrc + n] : 0.f;
  }
  __syncthreads();
  for (int i = 0; i < 32; i += 8) {
    int n = n0 + ty + i, k = k0 + tx;
    dst[(size_t)n * 1024 + k] = f2bf(tile[tx][ty + i]);
  }
}

// ------------- weight transpose, ALL 16 matrices (4 experts) in one launch --
struct W16 {
  const float* src[16];
  unsigned short* dst[16];
  int pd[4];
};
__global__ __launch_bounds__(256) void wtrans16_kernel(W16 p) {
  __shared__ float tile[32][33];
  int z = blockIdx.z;
  int e = z >> 2, m = z & 3;
  const float* src = p.src[z];
  unsigned short* dst = p.dst[z];
  int pd = p.pd[e];
  int ksrc = (m < 3) ? 1024 : pd;
  int nsrc = (m < 3) ? pd : 1024;
  int ldsrc = (m < 3) ? pd : 1024;
  int k0 = blockIdx.x * 32, n0 = blockIdx.y * 32;
  int tx = threadIdx.x & 31, ty = threadIdx.x >> 5;
  for (int i = 0; i < 32; i += 8) {
    int k = k0 + ty + i, n = n0 + tx;
    tile[ty + i][tx] = (k < ksrc && n < nsrc) ? src[(size_t)k * ldsrc + n] : 0.f;
  }
  __syncthreads();
  for (int i = 0; i < 32; i += 8) {
    int n = n0 + ty + i, k = k0 + tx;
    dst[(size_t)n * 1024 + k] = f2bf(tile[tx][ty + i]);
  }
}

// ------------------------------------------------------- bf16 MFMA GEMM -----
// (fallback path only; BK=32)
__global__ __launch_bounds__(256) void gemm_mfma(
    const unsigned short* __restrict__ A, const unsigned short* __restrict__ Bt,
    const float* __restrict__ b0, const float* __restrict__ b1,
    const float* __restrict__ b2, void* __restrict__ Cv, int ldc,
    int nact, int elu_ncut, int out_bf16, int mode,
    const float* __restrict__ gw, int expert, int remap,
    int qs_ncut, float qscale) {
  constexpr int K = 1024;
  __shared__ __align__(16) unsigned short As[128 * 32];
  __shared__ __align__(16) unsigned short Bs[128 * 32];
  int tid = threadIdx.x, wave = tid >> 6, lane = tid & 63;
  int quad = lane >> 4, lrow = lane & 15;
  int rw = (wave >> 1) * 64, cw = (wave & 1) * 64;
  int m0 = blockIdx.y * 128, n0 = blockIdx.x * 128;
  int srow = wave * 32 + (lane >> 2);
  int scol = (lane & 3) * 8;
  const unsigned short* gA = A + (size_t)(m0 + srow) * K + scol;
  const unsigned short* gB = Bt + (size_t)(n0 + srow) * K + scol;
  unsigned short* lA = &As[wave * 1024];
  unsigned short* lB = &Bs[wave * 1024];
  f32x4 acc[4][4];
#pragma unroll
  for (int mt = 0; mt < 4; ++mt)
#pragma unroll
    for (int nt = 0; nt < 4; ++nt) acc[mt][nt] = (f32x4){0.f, 0.f, 0.f, 0.f};

  for (int k0 = 0; k0 < K; k0 += 32) {
    gld16(gA + k0, lA);
    gld16(gA + 16 * K + k0, lA + 512);
    gld16(gB + k0, lB);
    gld16(gB + 16 * K + k0, lB + 512);
    __syncthreads();
    bf16x8 af[4], bfr[4];
#pragma unroll
    for (int t = 0; t < 4; ++t) {
      af[t]  = *(const bf16x8*)&As[(rw + t * 16 + lrow) * 32 + quad * 8];
      bfr[t] = *(const bf16x8*)&Bs[(cw + t * 16 + lrow) * 32 + quad * 8];
    }
#pragma unroll
    for (int mt = 0; mt < 4; ++mt)
#pragma unroll
      for (int nt = 0; nt < 4; ++nt)
        acc[mt][nt] = __builtin_amdgcn_mfma_f32_16x16x32_bf16(
            af[mt], bfr[nt], acc[mt][nt], 0, 0, 0);
    __syncthreads();
  }
#pragma unroll
  for (int nt = 0; nt < 4; ++nt) {
    int n = n0 + cw + nt * 16 + lrow;
    int slice = n >> 10, noff = n & 1023;
    if (noff >= nact) continue;
    const float* bp = (slice == 0) ? b0 : (slice == 1) ? b1 : b2;
    float bias = bp[noff];
    bool do_elu = n < elu_ncut;
    bool do_qs = n < qs_ncut;
    int col = n;
    if (remap) {
      int head = (noff * 12337) >> 20;  // noff/85 for noff<1020
      col = slice * 1152 + head * 96 + (noff - head * 85);
    }
#pragma unroll
    for (int mt = 0; mt < 4; ++mt) {
      int mb = m0 + rw + mt * 16 + quad * 4;
#pragma unroll
      for (int r = 0; r < 4; ++r) {
        int m = mb + r;
        float val = acc[mt][nt][r] + bias;
        if (do_elu) val = (val > 0.f) ? val + 1.f : expf(val);
        if (do_qs) val *= qscale;
        size_t ci = (size_t)m * ldc + col;
        if (out_bf16) {
          ((unsigned short*)Cv)[ci] = f2bf(val);
        } else {
          float* C = (float*)Cv;
          if (mode == 0) C[ci] = val;
          else {
            float g = gw[m * 4 + expert];
            if (mode == 1) C[ci] = g * val;
            else           C[ci] += g * val;
          }
        }
      }
    }
  }
}

// ============== 256x256 counted-prefetch GEMM core (K=1024) =================
// Minimal-2-phase recipe (T3 catalog, m248v2-verified): per K-tile,
//   STAGE(t+1 -> buf^1)  — issue FIRST (8 gld16/thread, stay in flight)
//   ds_read frags(buf cur) ; 2x {setprio(1) 32 MFMA setprio(0)}
//   __syncthreads()      — one barrier/tile; its vmcnt-drain is cheap because
//                          the loads had the full 64-MFMA phase to complete.
// LDS swizzle (T2, fixed to 3 row bits per G4): logical (row,c) ushort stored
// at col c ^ ((row&7)<<3)  — 16 lanes reading 16 rows at one col now hit 8
// distinct 16B slots (2 lanes/slot = free). global_load_lds writes LINEARLY,
// so the swizzle is realized by pre-swizzling the per-lane GLOBAL source col;
// ds_read applies the same XOR (both-sides, rule #21).
// Per-element accumulation is K-ascending (t, then ks) == old BK=32 kernel
// => bit-identical results; absmax is the canary.
__device__ __forceinline__ void stage_tile(
    const unsigned short* __restrict__ A, const unsigned short* __restrict__ Bt,
    int m0, int n0, int kbase, unsigned short* Abuf, unsigned short* Bbuf,
    int wave, int lane) {
#pragma unroll
  for (int j = 0; j < 2; ++j) {
    int t = j * 512 + wave * 64 + lane;      // 16B-slot id within half-tile
    int rl = t >> 3;                          // row 0..127 within half
    int c0 = ((t & 7) * 8) ^ ((rl & 7) << 3); // pre-swizzled source col
    int ldst = (j * 512 + wave * 64) * 8;     // wave-uniform LDS base (ushorts)
    gld16(A + (size_t)(m0 + rl) * 1024 + kbase + c0, Abuf + ldst);
    gld16(A + (size_t)(m0 + 128 + rl) * 1024 + kbase + c0, Abuf + 8192 + ldst);
    gld16(Bt + (size_t)(n0 + rl) * 1024 + kbase + c0, Bbuf + ldst);
    gld16(Bt + (size_t)(n0 + 128 + rl) * 1024 + kbase + c0, Bbuf + 8192 + ldst);
  }
}

__device__ __forceinline__ void gemm256_core(
    const unsigned short* __restrict__ A, const unsigned short* __restrict__ Bt,
    int m0, int n0, unsigned short* As, unsigned short* Bs,
    f32x4 (&acc)[8][4]) {
  int tid = threadIdx.x;
  int wave = tid >> 6, lane = tid & 63;
  int quad = lane >> 4, l15 = lane & 15;
  int wr = wave >> 2, wc = wave & 3;
#pragma unroll
  for (int mr = 0; mr < 8; ++mr)
#pragma unroll
    for (int nr = 0; nr < 4; ++nr) acc[mr][nr] = (f32x4){0.f, 0.f, 0.f, 0.f};
  stage_tile(A, Bt, m0, n0, 0, As, Bs, wave, lane);
  __syncthreads();
  int cur = 0;
  for (int t = 0; t < 16; ++t) {
    if (t + 1 < 16)
      stage_tile(A, Bt, m0, n0, (t + 1) * 64, As + (cur ^ 1) * 16384,
                 Bs + (cur ^ 1) * 16384, wave, lane);
    const unsigned short* Ar = As + cur * 16384;
    const unsigned short* Br = Bs + cur * 16384;
#pragma unroll
    for (int ks = 0; ks < 2; ++ks) {
      int c = ks * 32 + quad * 8;
      bf16x8 af[8], bfr[4];
#pragma unroll
      for (int i = 0; i < 8; ++i) {
        int row = wr * 128 + i * 16 + l15;
        af[i] = *(const bf16x8*)&Ar[row * 64 + (c ^ ((row & 7) << 3))];
      }
#pragma unroll
      for (int i = 0; i < 4; ++i) {
        int row = wc * 64 + i * 16 + l15;
        bfr[i] = *(const bf16x8*)&Br[row * 64 + (c ^ ((row & 7) << 3))];
      }
      __builtin_amdgcn_s_setprio(1);
#pragma unroll
      for (int mr = 0; mr < 8; ++mr)
#pragma unroll
        for (int nr = 0; nr < 4; ++nr)
          acc[mr][nr] = __builtin_amdgcn_mfma_f32_16x16x32_bf16(
              af[mr], bfr[nr], acc[mr][nr], 0, 0, 0);
      __builtin_amdgcn_s_setprio(0);
      __builtin_amdgcn_sched_barrier(0);  // keep ks=1 frag reads after ks=0
                                          // MFMAs (bounds VGPR, no spill)
    }
    __syncthreads();
    cur ^= 1;
  }
}

// --------------------------- merged QKV projection GEMM, z=expert -----------
struct QkvP {
  const unsigned short* Bt[4];
  const float* bq[4];
  const float* bk[4];
  const float* bv[4];
  unsigned short* C[4];
  int ldc[4];
  int nact[4];
  int elu_ncut[4];
  int remap[4];
  int qs_ncut[4];
  float qscale[4];
};
__global__ __launch_bounds__(512, 1) void gemm_qkv4_v2(
    const unsigned short* __restrict__ A, QkvP p) {
  __shared__ __align__(16) unsigned short As[2 * 256 * 64];
  __shared__ __align__(16) unsigned short Bs[2 * 256 * 64];
  int e = blockIdx.z;
  // XCD-aware bijective swizzle within expert slice (192 blocks, 192%8==0)
  int flat = blockIdx.y * 12 + blockIdx.x;
  int swz = (flat & 7) * 24 + (flat >> 3);
  int m0 = (swz / 12) * 256, n0 = (swz % 12) * 256;
  f32x4 acc[8][4];
  gemm256_core(A, p.Bt[e], m0, n0, As, Bs, acc);
  int nact = p.nact[e], elu_ncut = p.elu_ncut[e], remap = p.remap[e];
  int qs_ncut = p.qs_ncut[e], ldc = p.ldc[e];
  float qscale = p.qscale[e];
  unsigned short* Cv = p.C[e];
  int tid = threadIdx.x, wave = tid >> 6, lane = tid & 63;
  int quad = lane >> 4, l15 = lane & 15;
  int wr = wave >> 2, wc = wave & 3;
#pragma unroll
  for (int nr = 0; nr < 4; ++nr) {
    int n = n0 + wc * 64 + nr * 16 + l15;
    int slice = n >> 10, noff = n & 1023;
    if (noff >= nact) continue;
    const float* bp = (slice == 0) ? p.bq[e] : (slice == 1) ? p.bk[e] : p.bv[e];
    float bias = bp[noff];
    bool do_elu = n < elu_ncut;
    bool do_qs = n < qs_ncut;
    int col = n;
    if (remap) {
      int head = (noff * 12337) >> 20;  // noff/85 for noff<1020
      col = slice * 1152 + head * 96 + (noff - head * 85);
    }
#pragma unroll
    for (int mr = 0; mr < 8; ++mr) {
      int mb = m0 + wr * 128 + mr * 16 + quad * 4;
#pragma unroll
      for (int r = 0; r < 4; ++r) {
        int m = mb + r;
        float val = acc[mr][nr][r] + bias;
        if (do_elu) val = (val > 0.f) ? val + 1.f : expf(val);
        if (do_qs) val *= qscale;
        Cv[(size_t)m * ldc + col] = f2bf(val);
      }
    }
  }
}

// ------------------------------------- merged output projection, z=expert ---
struct OutP {
  const unsigned short* A[4];
  const unsigned short* B[4];
  const float* bias[4];
};
__global__ __launch_bounds__(512, 1) void gemm_out4_v2(
    OutP p, const float* __restrict__ gw, float* __restrict__ part) {
  __shared__ __align__(16) unsigned short As[2 * 256 * 64];
  __shared__ __align__(16) unsigned short Bs[2 * 256 * 64];
  int e = blockIdx.z;
  int flat = blockIdx.y * 4 + blockIdx.x;  // 64 blocks, 64%8==0
  int swz = (flat & 7) * 8 + (flat >> 3);
  int m0 = (swz / 4) * 256, n0 = (swz % 4) * 256;
  f32x4 acc[8][4];
  gemm256_core(p.A[e], p.B[e], m0, n0, As, Bs, acc);
  const float* bp = p.bias[e];
  float* C = part + (size_t)e * (4096ull * 1024ull);
  int tid = threadIdx.x, wave = tid >> 6, lane = tid & 63;
  int quad = lane >> 4, l15 = lane & 15;
  int wr = wave >> 2, wc = wave & 3;
#pragma unroll
  for (int nr = 0; nr < 4; ++nr) {
    int n = n0 + wc * 64 + nr * 16 + l15;
    float bias = bp[n];
#pragma unroll
    for (int mr = 0; mr < 8; ++mr) {
      int mb = m0 + wr * 128 + mr * 16 + quad * 4;
#pragma unroll
      for (int r = 0; r < 4; ++r) {
        int m = mb + r;
        float g = gw[m * 4 + e];
        C[(size_t)m * 1024 + n] = g * (acc[mr][nr][r] + bias);
      }
    }
  }
}

// part[e] summed in expert order -> identical rounding to old mode1/mode2 chain
__global__ __launch_bounds__(256) void reduce4(
    const float* __restrict__ part, float* __restrict__ out) {
  constexpr size_t N = 4096ull * 1024ull;
  size_t idx = ((size_t)blockIdx.x * 256 + threadIdx.x) * 4;
  f32x4 a0 = *(const f32x4*)(part + idx);
  f32x4 a1 = *(const f32x4*)(part + idx + N);
  f32x4 a2 = *(const f32x4*)(part + idx + 2 * N);
  f32x4 a3 = *(const f32x4*)(part + idx + 3 * N);
  f32x4 s;
#pragma unroll
  for (int j = 0; j < 4; ++j) {
    float t = a0[j];
    t += a1[j]; t += a2[j]; t += a3[j];
    s[j] = t;
  }
  *(f32x4*)(out + idx) = s;
}

// ----- zero never-written pad columns (e1 head-pad 85..95, aob1 1020..1023) -
__global__ __launch_bounds__(256) void padzero(
    unsigned short* __restrict__ qkv1, unsigned short* __restrict__ aob1) {
  int idx = blockIdx.x * 256 + threadIdx.x;  // grid covers 4096*396 exactly
  int m = idx / 396, r = idx % 396;
  int slice = r / 132, r2 = r % 132;
  int head = r2 / 11, c = 85 + r2 % 11;
  qkv1[(size_t)m * 3456 + slice * 1152 + head * 96 + c] = 0;
  if (idx < 4096 * 4) {
    int mm = idx >> 2, cc = 1020 + (idx & 3);
    aob1[(size_t)mm * 1024 + cc] = 0;
  }
}

// --------------------------------------------- MFMA flash attention v6 ------
// 512 thr, QT=256, double-buffered Ks/Vt, one barrier per KT-iteration.
template <int HD, bool LOCAL>
__device__ __forceinline__ void attn_body(
    char* smem,
    const unsigned short* __restrict__ q, const unsigned short* __restrict__ k,
    const unsigned short* __restrict__ v, const int* __restrict__ amask,
    unsigned short* __restrict__ ao, int ldq, int h) {
  constexpr int HDP = (HD + 31) & ~31;  // 128 or 96
  constexpr int DCH = HDP / 32;         // 4 or 3
  constexpr int NDT = HDP / 16;         // 8 or 6
  constexpr int NCH = HDP / 8;          // 16 or 12
  constexpr int QT = 256, KT = 64;
  constexpr int KLD = HDP + 8;
  constexpr int VLD = KT + 4;
  constexpr int W2 = 32;
  constexpr int KSZ = KT * KLD;   // ushorts per K buffer
  constexpr int VSZ = HDP * VLD;  // halves per V buffer
  unsigned short* Ks = (unsigned short*)smem;              // [2][KSZ]
  _Float16* Vt = (_Float16*)(smem + 2 * KSZ * 2);          // [2][VSZ]
  unsigned long long* amq =
      (unsigned long long*)(smem + 2 * KSZ * 2 + 2 * VSZ * 2);
  int tid = threadIdx.x, wave = tid >> 6, lane = tid & 63;
  int quad = lane >> 4, l15 = lane & 15;
  int q0 = blockIdx.x * QT, b = blockIdx.z;
  size_t baseq = ((size_t)b * S_) * ldq + (size_t)h * HDP;
  size_t baseo = ((size_t)b * S_) * H_ + (size_t)h * HD;

  {
    unsigned long long bb0 = __ballot(amask[b * S_ + wave * 128 + lane] != 0);
    unsigned long long bb1 = __ballot(amask[b * S_ + wave * 128 + 64 + lane] != 0);
    if (lane == 0) { amq[wave * 2] = bb0; amq[wave * 2 + 1] = bb1; }
  }

  int qrow[2];
  bf16x8 qf[2][DCH];
#pragma unroll
  for (int g = 0; g < 2; ++g) {
    qrow[g] = q0 + wave * 32 + g * 16 + l15;
#pragma unroll
    for (int c = 0; c < DCH; ++c)
#pragma unroll
      for (int j = 0; j < 8; ++j) {
        int d = c * 32 + quad * 8 + j;
        qf[g][c][j] =
            (d < HD) ? (short)q[baseq + (size_t)qrow[g] * ldq + d] : (short)0;
      }
  }

  int jlo = 0, jhi = S_;
  if (LOCAL) {
    jlo = q0 - W2; if (jlo < 0) jlo = 0; jlo &= ~(KT - 1);
    jhi = q0 + QT + W2; if (jhi > S_) jhi = S_;
  }

  int skey = tid & 63, sc8a = tid >> 6, sc8b = 8 + (tid >> 6);
  bool sactb = sc8b < NCH;
  const unsigned short* kg = k + baseq + (size_t)skey * ldq;
  const unsigned short* vg = v + baseq + (size_t)skey * ldq;
  bf16x8 kra = {}, krb = {}, vra = {}, vrb = {};
  {
    size_t o = (size_t)jlo * ldq;
    kra = *(const bf16x8*)(kg + o + sc8a * 8);
    vra = *(const bf16x8*)(vg + o + sc8a * 8);
    if (sactb) {
      krb = *(const bf16x8*)(kg + o + sc8b * 8);
      vrb = *(const bf16x8*)(vg + o + sc8b * 8);
    }
  }

  // prologue: stage tile jlo into buffer 0
  {
    *(bf16x8*)&Ks[skey * KLD + sc8a * 8] = kra;
#pragma unroll
    for (int j = 0; j < 8; ++j)
      Vt[(sc8a * 8 + j) * VLD + skey] = (_Float16)bf2f((unsigned short)vra[j]);
    if (sactb) {
      *(bf16x8*)&Ks[skey * KLD + sc8b * 8] = krb;
#pragma unroll
      for (int j = 0; j < 8; ++j)
        Vt[(sc8b * 8 + j) * VLD + skey] = (_Float16)bf2f((unsigned short)vrb[j]);
    }
  }
  int cur = 0;
  __syncthreads();

  float m_run[2] = {-1e30f, -1e30f}, l_run[2] = {0.f, 0.f};
  f32x4 accd[2][NDT];
#pragma unroll
  for (int g = 0; g < 2; ++g)
#pragma unroll
    for (int dt = 0; dt < NDT; ++dt) accd[g][dt] = (f32x4){0.f, 0.f, 0.f, 0.f};

  for (int j0 = jlo; j0 < jhi; j0 += KT) {
    int jn = j0 + KT;
    if (jn < jhi) {
      size_t o = (size_t)jn * ldq;
      kra = *(const bf16x8*)(kg + o + sc8a * 8);
      vra = *(const bf16x8*)(vg + o + sc8a * 8);
      if (sactb) {
        krb = *(const bf16x8*)(kg + o + sc8b * 8);
        vrb = *(const bf16x8*)(vg + o + sc8b * 8);
      }
    }
    const unsigned short* KsR = Ks + cur * KSZ;
    const _Float16* VtR = Vt + cur * VSZ;
    f32x4 sf[2][4];
#pragma unroll
    for (int kt = 0; kt < 4; ++kt) {
      sf[0][kt] = (f32x4){0.f, 0.f, 0.f, 0.f};
      sf[1][kt] = (f32x4){0.f, 0.f, 0.f, 0.f};
#pragma unroll
      for (int c = 0; c < DCH; ++c) {
        bf16x8 kf = *(const bf16x8*)&KsR[(kt * 16 + l15) * KLD + c * 32 + quad * 8];
        sf[0][kt] = __builtin_amdgcn_mfma_f32_16x16x32_bf16(kf, qf[0][c], sf[0][kt], 0, 0, 0);
        sf[1][kt] = __builtin_amdgcn_mfma_f32_16x16x32_bf16(kf, qf[1][c], sf[1][kt], 0, 0, 0);
      }
    }
    unsigned long long mb = amq[j0 >> 6];
    unsigned mw[2] = {(unsigned)mb, (unsigned)(mb >> 32)};
    float pvv[2][4][4];
    float mx[2] = {-1e30f, -1e30f};
#pragma unroll
    for (int kt = 0; kt < 4; ++kt) {
      unsigned word = mw[kt >> 1];
      int sh = (kt & 1) * 16 + quad * 4;
#pragma unroll
      for (int r = 0; r < 4; ++r) {
        bool okm = (word >> (sh + r)) & 1;
#pragma unroll
        for (int g = 0; g < 2; ++g) {
          bool ok = okm;
          if (LOCAL) {
            int dj = (j0 + kt * 16 + quad * 4 + r) - qrow[g];
            ok = ok && (dj <= W2) && (dj >= -W2);
          }
          float s = ok ? sf[g][kt][r] : -1e30f;
          pvv[g][kt][r] = s;
          mx[g] = fmaxf(mx[g], s);
        }
      }
    }
    half4 pf[2][4];
    float aR[2][4];
#pragma unroll
    for (int g = 0; g < 2; ++g) {
      float mxg = fmaxf(mx[g], __shfl_xor(mx[g], 16));
      mxg = fmaxf(mxg, __shfl_xor(mxg, 32));
      float m_new = fmaxf(m_run[g], mxg);
      float psum = 0.f;
#pragma unroll
      for (int kt = 0; kt < 4; ++kt)
#pragma unroll
        for (int r = 0; r < 4; ++r) {
          float s = pvv[g][kt][r];
          float p = (s > -1e29f) ? __builtin_amdgcn_exp2f(s - m_new) : 0.f;
          pvv[g][kt][r] = p;
          psum += p;
        }
      psum += __shfl_xor(psum, 16);
      psum += __shfl_xor(psum, 32);
      float alpha = __builtin_amdgcn_exp2f(m_run[g] - m_new);
      m_run[g] = m_new;
      l_run[g] = l_run[g] * alpha + psum;
#pragma unroll
      for (int r = 0; r < 4; ++r)
        aR[g][r] = __shfl(alpha, (lane & 48) | (quad * 4 + r));
#pragma unroll
      for (int dt = 0; dt < NDT; ++dt)
#pragma unroll
        for (int r = 0; r < 4; ++r) accd[g][dt][r] *= aR[g][r];
#pragma unroll
      for (int kt = 0; kt < 4; ++kt)
#pragma unroll
        for (int r = 0; r < 4; ++r) pf[g][kt][r] = (_Float16)pvv[g][kt][r];
    }
    if (jn < jhi) {
      unsigned short* KsW = Ks + (cur ^ 1) * KSZ;
      _Float16* VtW = Vt + (cur ^ 1) * VSZ;
      *(bf16x8*)&KsW[skey * KLD + sc8a * 8] = kra;
#pragma unroll
      for (int j = 0; j < 8; ++j)
        VtW[(sc8a * 8 + j) * VLD + skey] = (_Float16)bf2f((unsigned short)vra[j]);
      if (sactb) {
        *(bf16x8*)&KsW[skey * KLD + sc8b * 8] = krb;
#pragma unroll
        for (int j = 0; j < 8; ++j)
          VtW[(sc8b * 8 + j) * VLD + skey] = (_Float16)bf2f((unsigned short)vrb[j]);
      }
    }
#pragma unroll
    for (int dt = 0; dt < NDT; ++dt)
#pragma unroll
      for (int kt = 0; kt < 4; ++kt) {
        half4 vf = *(const half4*)&VtR[(dt * 16 + l15) * VLD + kt * 16 + quad * 4];
        accd[0][dt] = __builtin_amdgcn_mfma_f32_16x16x16f16(pf[0][kt], vf, accd[0][dt], 0, 0, 0);
        accd[1][dt] = __builtin_amdgcn_mfma_f32_16x16x16f16(pf[1][kt], vf, accd[1][dt], 0, 0, 0);
      }
    __syncthreads();
    cur ^= 1;
  }
#pragma unroll
  for (int g = 0; g < 2; ++g) {
    float linv = (l_run[g] > 0.f) ? 1.f / l_run[g] : 0.f;
    float lR[4];
#pragma unroll
    for (int r = 0; r < 4; ++r)
      lR[r] = __shfl(linv, (lane & 48) | (quad * 4 + r));
#pragma unroll
    for (int dt = 0; dt < NDT; ++dt) {
      int d = dt * 16 + l15;
      if (d >= HD) continue;
#pragma unroll
      for (int r = 0; r < 4; ++r) {
        int row = q0 + wave * 32 + g * 16 + quad * 4 + r;
        ao[baseo + (size_t)row * H_ + d] = f2bf(accd[g][dt][r] * lR[r]);
      }
    }
  }
}

template <int HD, bool LOCAL>
__global__ __launch_bounds__(512) void attn_mfma3(
    const unsigned short* __restrict__ q, const unsigned short* __restrict__ k,
    const unsigned short* __restrict__ v, const int* __restrict__ amask,
    unsigned short* __restrict__ ao, int ldq) {
  constexpr int HDP = (HD + 31) & ~31;
  __shared__ __align__(16) char smem[2 * 64 * (HDP + 8) * 2 + 2 * HDP * 68 * 2 + 128];
  attn_body<HD, LOCAL>(smem, q, k, v, amask, ao, ldq, blockIdx.y);
}

// ------------------------------------------------------ linear attention ----
#define NSPLIT 4
__device__ __forceinline__ void linkv_body(
    char* smemi, const unsigned short* __restrict__ k,
    const unsigned short* __restrict__ v, float* __restrict__ kvp,
    float* __restrict__ ksump, int ld, int h, int b, int split, int tid) {
  constexpr int HD = 128;
  constexpr int TLD = 34;
  unsigned short* Kt = (unsigned short*)smemi;           // 8704 B
  unsigned short* Vt = Kt + HD * TLD;                    // 8704 B
  int bh = b * 8 + h;
  int wave = tid >> 6, lane = tid & 63;
  int quad = lane >> 4, l15 = lane & 15;
  int rw = (wave >> 1) * 64, cw = (wave & 1) * 64;
  size_t base = ((size_t)b * S_) * ld + (size_t)h * HD;
  int s_begin = split * (S_ / NSPLIT);

  f32x4 acc[4][4];
#pragma unroll
  for (int mt = 0; mt < 4; ++mt)
#pragma unroll
    for (int nt = 0; nt < 4; ++nt) acc[mt][nt] = (f32x4){0.f, 0.f, 0.f, 0.f};
  float ksacc = 0.f;
  int myd = tid & 127, half = tid >> 7;

  for (int c0 = 0; c0 < S_ / NSPLIT; c0 += 32) {
    for (int idx = tid; idx < 32 * HD; idx += 256) {
      int d = idx & 127, s = idx >> 7;
      size_t g = base + (size_t)(s_begin + c0 + s) * ld + d;
      Kt[d * TLD + s] = k[g];
      Vt[d * TLD + s] = v[g];
    }
    __syncthreads();
    bf16x8 af[4], bf[4];
#pragma unroll
    for (int t = 0; t < 4; ++t) {
      af[t] = *(const bf16x8*)&Vt[(rw + t * 16 + l15) * TLD + quad * 8];
      bf[t] = *(const bf16x8*)&Kt[(cw + t * 16 + l15) * TLD + quad * 8];
    }
#pragma unroll
    for (int mt = 0; mt < 4; ++mt)
#pragma unroll
      for (int nt = 0; nt < 4; ++nt)
        acc[mt][nt] = __builtin_amdgcn_mfma_f32_16x16x32_bf16(
            af[mt], bf[nt], acc[mt][nt], 0, 0, 0);
#pragma unroll
    for (int s = 0; s < 16; ++s)
      ksacc += bf2f(Kt[myd * TLD + half * 16 + s]);
    __syncthreads();
  }
  float* red = (float*)Kt;
  if (half == 1) red[myd] = ksacc;
  __syncthreads();
  if (half == 0)
    ksump[((size_t)split * 32 + bh) * HD + myd] = ksacc + red[myd];
  float* kvo = kvp + ((size_t)split * 32 + bh) * (HD * HD);
#pragma unroll
  for (int mt = 0; mt < 4; ++mt)
#pragma unroll
    for (int nt = 0; nt < 4; ++nt) {
      int dk = cw + nt * 16 + l15;
#pragma unroll
      for (int r = 0; r < 4; ++r) {
        int dv = rw + mt * 16 + quad * 4 + r;
        kvo[(size_t)dv * HD + dk] = acc[mt][nt][r];
      }
    }
}

__global__ __launch_bounds__(256) void linkv_mfma(
    const unsigned short* __restrict__ k, const unsigned short* __restrict__ v,
    float* __restrict__ kvp, float* __restrict__ ksump, int ld) {
  __shared__ __align__(16) char smemi[17408];
  linkv_body(smemi, k, v, kvp, ksump, ld, blockIdx.x, blockIdx.y, blockIdx.z,
             threadIdx.x);
}

// one launch: e0 (y<8) + e1 (y<20) + e3 local (y<28) + linkv e2 (y<32,
// two 256-thr instances per block). Grid (4, 32, 4) = 512 blocks = 2/CU.
__global__ __launch_bounds__(512) void attn_mega(
    const unsigned short* __restrict__ qkv0,
    const unsigned short* __restrict__ qkv1,
    const unsigned short* __restrict__ qkv2,
    const unsigned short* __restrict__ qkv3, const int* __restrict__ amask,
    unsigned short* __restrict__ ao0, unsigned short* __restrict__ ao1,
    unsigned short* __restrict__ ao3,
    float* __restrict__ kvp, float* __restrict__ ksump) {
  __shared__ __align__(16) char smem[69760];
  int y = blockIdx.y;
  if (y < 8)
    attn_body<128, false>(smem, qkv0, qkv0 + 1024, qkv0 + 2048, amask, ao0,
                          3072, y);
  else if (y < 20)
    attn_body<85, false>(smem, qkv1, qkv1 + 1152, qkv1 + 2304, amask, ao1,
                         3456, y - 8);
  else if (y < 28)
    attn_body<128, true>(smem, qkv3, qkv3 + 1024, qkv3 + 2048, amask, ao3,
                         3072, y - 20);
  else {
    int sub = threadIdx.x >> 8, stid = threadIdx.x & 255;
    int idx = (y - 28) * 8 + blockIdx.x * 2 + sub;  // 32 combos per b
    linkv_body(smem + sub * 17408, qkv2 + 1024, qkv2 + 2048, kvp, ksump, 3072,
               idx & 7, blockIdx.z, idx >> 3, stid);
  }
}

__global__ __launch_bounds__(256) void linkv_reduce(
    const float* __restrict__ kvp, const float* __restrict__ ksump,
    unsigned short* __restrict__ kvb, float* __restrict__ ksum) {
  int idx = blockIdx.x * 256 + threadIdx.x;
  float s = 0.f;
#pragma unroll
  for (int p = 0; p < NSPLIT; ++p) s += kvp[(size_t)p * (32 * 128 * 128) + idx];
  kvb[idx] = f2bf(s);
  if (idx < 32 * 128) {
    float t = 0.f;
#pragma unroll
    for (int p = 0; p < NSPLIT; ++p) t += ksump[(size_t)p * (32 * 128) + idx];
    ksum[idx] = t;
  }
}

__global__ __launch_bounds__(256) void linattn_mfma(
    const unsigned short* __restrict__ q, const unsigned short* __restrict__ kvT,
    const float* __restrict__ ksum, unsigned short* __restrict__ ao, int ldq) {
  constexpr int KLD = 136;
  __shared__ __align__(16) unsigned short Ks[128 * KLD];
  __shared__ float ksL[128];
  int tid = threadIdx.x, wave = tid >> 6, lane = tid & 63;
  int quad = lane >> 4, l15 = lane & 15;
  int rw = (wave >> 1) * 64, cw = (wave & 1) * 64;
  int q0 = blockIdx.x * 128, h = blockIdx.y, b = blockIdx.z;
  int bh = b * 8 + h;
  size_t baseq = ((size_t)b * S_) * ldq + (size_t)h * 128;
  size_t baseo = ((size_t)b * S_) * H_ + (size_t)h * 128;
  const unsigned short* kvg = kvT + (size_t)bh * (128 * 128);
  for (int idx = tid; idx < 128 * 16; idx += 256) {
    int e = idx >> 4, c = idx & 15;
    *(bf16x8*)&Ks[e * KLD + c * 8] = *(const bf16x8*)&kvg[e * 128 + c * 8];
  }
  if (tid < 128) ksL[tid] = ksum[(size_t)bh * 128 + tid];
  bf16x8 qf[4][4];
#pragma unroll
  for (int mt = 0; mt < 4; ++mt) {
    const unsigned short* qr = q + baseq + (size_t)(q0 + rw + mt * 16 + l15) * ldq;
#pragma unroll
    for (int kc = 0; kc < 4; ++kc)
      qf[mt][kc] = *(const bf16x8*)&qr[kc * 32 + quad * 8];
  }
  __syncthreads();
  f32x4 acc[4][4];
#pragma unroll
  for (int mt = 0; mt < 4; ++mt)
#pragma unroll
    for (int nt = 0; nt < 4; ++nt) acc[mt][nt] = (f32x4){0.f, 0.f, 0.f, 0.f};
#pragma unroll
  for (int kc = 0; kc < 4; ++kc) {
    bf16x8 bf[4];
#pragma unroll
    for (int nt = 0; nt < 4; ++nt)
      bf[nt] = *(const bf16x8*)&Ks[(cw + nt * 16 + l15) * KLD + kc * 32 + quad * 8];
#pragma unroll
    for (int mt = 0; mt < 4; ++mt)
#pragma unroll
      for (int nt = 0; nt < 4; ++nt)
        acc[mt][nt] = __builtin_amdgcn_mfma_f32_16x16x32_bf16(
            qf[mt][kc], bf[nt], acc[mt][nt], 0, 0, 0);
  }
  float den[4];
#pragma unroll
  for (int mt = 0; mt < 4; ++mt) {
    float s = 0.f;
#pragma unroll
    for (int kc = 0; kc < 4; ++kc)
#pragma unroll
      for (int j = 0; j < 8; ++j)
        s += bf2f((unsigned short)qf[mt][kc][j]) * ksL[kc * 32 + quad * 8 + j];
    s += __shfl_xor(s, 16);
    s += __shfl_xor(s, 32);
    den[mt] = s;
  }
#pragma unroll
  for (int mt = 0; mt < 4; ++mt)
#pragma unroll
    for (int r = 0; r < 4; ++r) {
      float dv = __shfl(den[mt], (lane & 48) | (quad * 4 + r));
      float inv = 1.f / (dv + 1e-6f);
      int row = q0 + rw + mt * 16 + quad * 4 + r;
#pragma unroll
      for (int nt = 0; nt < 4; ++nt) {
        int col = cw + nt * 16 + l15;
        ao[baseo + (size_t)row * H_ + col] = f2bf(acc[mt][nt][r] * inv);
      }
    }
}

// ---------------------------------------------------------------- launch ----
extern "C" void kernel_launch(void* const* d_in, const int* in_sizes, int n_in,
                              void* d_out, int out_size, void* d_ws, size_t ws_size,
                              hipStream_t stream) {
  const float* x = (const float*)d_in[0];
  const float* Wg = (const float*)d_in[1];
  const int* amask = (const int*)d_in[34];
  float* out = (float*)d_out;
  char* ws = (char*)d_ws;
  const size_t MiB = 1ull << 20;
  const int nhs[4] = {8, 12, 8, 8};
  const float LOG2E = 1.4426950408889634f;

  if (ws_size >= 157 * MiB) {
    // ---- merged schedule. Aliasing plan (stream-ordered live ranges):
    //   kvp    @ 4 MiB  (8 MiB)  over xb     — xb dead after gemm_qkv4;
    //          attn_mega's linkv instances write kvp (after gemm_qkv4 ✓)
    //   ksump  @ 12 MiB (64 KB)
    //   qkvT4  @ 125 MiB (24 MiB) over aobE[0..2] — dead after gemm_qkv4;
    //          padzero runs AFTER gemm_qkv4; attn rewrites aobE afterwards.
    //   part   @ 26 MiB (64 MiB) over qkvE[0..2] — dead after attn/linattn.
    float* gw = (float*)ws;                                  // 64 KB
    float* ksum = (float*)(ws + (64ull << 10));              // 16 KB
    unsigned short* kvb = (unsigned short*)(ws + 1 * MiB);   // 1 MiB
    unsigned short* xb = (unsigned short*)(ws + 4 * MiB);    // 8 MiB
    float* kvp = (float*)(ws + 4 * MiB);                     // 8 MiB (alias xb)
    float* ksump = (float*)(ws + 12 * MiB);                  // 64 KB
    unsigned short* woT[4];
    for (int e = 0; e < 4; ++e)
      woT[e] = (unsigned short*)(ws + (18 + 2 * e) * MiB);   // 8 MiB
    const size_t qkvOff[4] = {26 * MiB, 50 * MiB, 77 * MiB, 101 * MiB};
    unsigned short* qkvE[4];
    for (int e = 0; e < 4; ++e) qkvE[e] = (unsigned short*)(ws + qkvOff[e]);
    float* part = (float*)(ws + 26 * MiB);                   // 64 MiB (alias qkvE)
    unsigned short* aobE[4];
    for (int e = 0; e < 4; ++e)
      aobE[e] = (unsigned short*)(ws + (125 + 8 * e) * MiB); // 32 MiB total
    unsigned short* qkvT4 = (unsigned short*)(ws + 125 * MiB); // 24 MiB (alias)

    gate_conv_kernel<<<4096, 64, 0, stream>>>(x, Wg, gw, xb);

    // all 16 weight transposes in one launch
    W16 w;
    for (int e = 0; e < 4; ++e) {
      w.pd[e] = nhs[e] * (H_ / nhs[e]);
      for (int m = 0; m < 3; ++m) {
        w.src[e * 4 + m] = (const float*)d_in[2 + 8 * e + 2 * m];  // Wq,Wk,Wv
        w.dst[e * 4 + m] = qkvT4 + (size_t)(e * 3 + m) * (1 << 20);
      }
      w.src[e * 4 + 3] = (const float*)d_in[2 + 8 * e + 6];        // Wo
      w.dst[e * 4 + 3] = woT[e];
    }
    wtrans16_kernel<<<dim3(32, 32, 16), 256, 0, stream>>>(w);

    // all 4 QKV projections in one launch (256² counted-prefetch)
    QkvP qp;
    for (int e = 0; e < 4; ++e) {
      int hd = H_ / nhs[e];
      int pd = nhs[e] * hd;
      qp.Bt[e] = qkvT4 + (size_t)(e * 3) * (1 << 20);
      qp.bq[e] = (const float*)d_in[2 + 8 * e + 1];
      qp.bk[e] = (const float*)d_in[2 + 8 * e + 3];
      qp.bv[e] = (const float*)d_in[2 + 8 * e + 5];
      qp.C[e] = qkvE[e];
      qp.ldc[e] = (e == 1) ? 3456 : 3072;
      qp.nact[e] = (pd == 1020) ? 1020 : 1024;
      qp.elu_ncut[e] = (e == 2) ? 2048 : 0;
      qp.remap[e] = (e == 1) ? 1 : 0;
      qp.qs_ncut[e] = (e == 2) ? 0 : 1024;
      qp.qscale[e] = LOG2E / sqrtf((float)hd);
    }
    gemm_qkv4_v2<<<dim3(12, 16, 4), 512, 0, stream>>>(xb, qp);

    // zero pad cols AFTER qkvT4 (aliasing aobE) is dead
    padzero<<<6336, 256, 0, stream>>>(qkvE[1], aobE[1]);

    // merged attention + linkv (kvp clobbers xb — dead now)
    attn_mega<<<dim3(S_ / 256, 32, B_), 512, 0, stream>>>(
        qkvE[0], qkvE[1], qkvE[2], qkvE[3], amask, aobE[0], aobE[1], aobE[3],
        kvp, ksump);

    linkv_reduce<<<(32 * 128 * 128) / 256, 256, 0, stream>>>(kvp, ksump, kvb, ksum);
    linattn_mfma<<<dim3(S_ / 128, 8, B_), 256, 0, stream>>>(
        qkvE[2], kvb, ksum, aobE[2], 3072);

    OutP p;
    for (int e = 0; e < 4; ++e) {
      p.A[e] = aobE[e];
      p.B[e] = woT[e];
      p.bias[e] = (const float*)d_in[2 + 8 * e + 7];
    }
    gemm_out4_v2<<<dim3(4, 16, 4), 512, 0, stream>>>(p, gw, part);
    reduce4<<<4096, 256, 0, stream>>>(part, out);
    return;
  }

  // ---- fallback: original sequential schedule (74 MiB workspace) ----
  float* gw            = (float*)(ws + 0);
  unsigned short* kvb  = (unsigned short*)(ws + (1ull << 20));
  float* ksum          = (float*)(ws + (3ull << 20) + (1ull << 19));
  unsigned short* xb   = (unsigned short*)(ws + (4ull << 20));
  unsigned short* qkvT = (unsigned short*)(ws + (12ull << 20));
  unsigned short* woT  = (unsigned short*)(ws + (18ull << 20));
  unsigned short* qkv  = (unsigned short*)(ws + (20ull << 20));
  unsigned short* aob  = (unsigned short*)(ws + (49ull << 20));
  float* kvp           = (float*)(ws + (57ull << 20));
  float* ksump         = (float*)(ws + (73ull << 20));

  conv_kernel<<<16384, 256, 0, stream>>>(x, xb, 1024, 1024);
  gate_kernel<<<4096, 64, 0, stream>>>(x, Wg, gw);

  for (int e = 0; e < 4; ++e) {
    const float* Wq = (const float*)d_in[2 + 8 * e + 0];
    const float* bq = (const float*)d_in[2 + 8 * e + 1];
    const float* Wk = (const float*)d_in[2 + 8 * e + 2];
    const float* bk = (const float*)d_in[2 + 8 * e + 3];
    const float* Wv = (const float*)d_in[2 + 8 * e + 4];
    const float* bv = (const float*)d_in[2 + 8 * e + 5];
    const float* Wo = (const float*)d_in[2 + 8 * e + 6];
    const float* bo = (const float*)d_in[2 + 8 * e + 7];
    int nh = nhs[e];
    int hd = H_ / nh;
    int pd = nh * hd;
    int ldqkv = (e == 1) ? 3456 : 3072;
    int qs_ncut = (e == 2) ? 0 : 1024;
    float qscale = LOG2E / sqrtf((float)hd);

    wtrans4_kernel<<<dim3(32, 32, 4), 256, 0, stream>>>(
        Wq, Wk, Wv, Wo, qkvT, qkvT + (1 << 20), qkvT + (2 << 20), woT, pd);

    gemm_mfma<<<dim3(24, 32), 256, 0, stream>>>(
        xb, qkvT, bq, bk, bv, qkv, ldqkv,
        (pd == 1020) ? 1020 : 1024, (e == 2) ? 2048 : 0, 1, 0, nullptr, 0,
        (e == 1) ? 1 : 0, qs_ncut, qscale);

    if (e == 2) {
      const unsigned short* qb = qkv;
      const unsigned short* kb = qkv + 1024;
      const unsigned short* vb = qkv + 2048;
      linkv_mfma<<<dim3(8, B_, NSPLIT), 256, 0, stream>>>(kb, vb, kvp, ksump, 3072);
      linkv_reduce<<<(32 * 128 * 128) / 256, 256, 0, stream>>>(kvp, ksump, kvb, ksum);
      linattn_mfma<<<dim3(S_ / 128, 8, B_), 256, 0, stream>>>(qb, kvb, ksum, aob, 3072);
    } else if (e == 1) {
      attn_mfma3<85, false><<<dim3(S_ / 256, 12, B_), 512, 0, stream>>>(
          qkv, qkv + 1152, qkv + 2304, amask, aob, 3456);
    } else if (e == 3) {
      attn_mfma3<128, true><<<dim3(S_ / 256, 8, B_), 512, 0, stream>>>(
          qkv, qkv + 1024, qkv + 2048, amask, aob, 3072);
    } else {
      attn_mfma3<128, false><<<dim3(S_ / 256, 8, B_), 512, 0, stream>>>(
          qkv, qkv + 1024, qkv + 2048, amask, aob, 3072);
    }

    gemm_mfma<<<dim3(8, 32), 256, 0, stream>>>(
        aob, woT, bo, bo, bo, out, 1024, 1024, 0, 0, (e == 0) ? 1 : 2, gw, e, 0,
        0, 1.0f);
  }
}

// Round 10
// 538.242 us; speedup vs baseline: 1.0439x; 1.0439x over previous
//
#include <hip/hip_runtime.h>
#include <cmath>

#define B_ 4
#define S_ 1024
#define H_ 1024

typedef short bf16x8 __attribute__((ext_vector_type(8)));
typedef float f32x4 __attribute__((ext_vector_type(4)));
typedef _Float16 half4 __attribute__((ext_vector_type(4)));

__device__ __forceinline__ unsigned short f2bf(float f) {
  unsigned u = __float_as_uint(f);
  u += 0x7fff + ((u >> 16) & 1);  // RTNE
  return (unsigned short)(u >> 16);
}
__device__ __forceinline__ float bf2f(unsigned short h) {
  return __uint_as_float(((unsigned)h) << 16);
}
__device__ __forceinline__ void gld16(const void* g, void* l) {
  __builtin_amdgcn_global_load_lds(
      (const __attribute__((address_space(1))) unsigned int*)g,
      (__attribute__((address_space(3))) unsigned int*)l, 16, 0, 0);
}

// ---------------------------------------------------------------- gating ----
__global__ __launch_bounds__(64) void gate_kernel(
    const float* __restrict__ x, const float* __restrict__ Wg,
    float* __restrict__ gw) {
  int t = blockIdx.x;
  int lane = threadIdx.x;
  const float* xr = x + (size_t)t * H_;
  float a0 = 0.f, a1 = 0.f, a2 = 0.f, a3 = 0.f;
  for (int h = lane; h < H_; h += 64) {
    float xv = xr[h];
    const float* wr = Wg + h * 4;
    a0 += xv * wr[0]; a1 += xv * wr[1]; a2 += xv * wr[2]; a3 += xv * wr[3];
  }
  for (int off = 32; off > 0; off >>= 1) {
    a0 += __shfl_down(a0, off);
    a1 += __shfl_down(a1, off);
    a2 += __shfl_down(a2, off);
    a3 += __shfl_down(a3, off);
  }
  if (lane == 0) {
    float v[4] = {a0, a1, a2, a3};
    int i0 = 0; float b0 = v[0];
    for (int e = 1; e < 4; ++e) if (v[e] > b0) { b0 = v[e]; i0 = e; }
    int i1 = -1; float b1 = -INFINITY;
    for (int e = 0; e < 4; ++e) { if (e == i0) continue; if (v[e] > b1) { b1 = v[e]; i1 = e; } }
    float e1v = expf(b1 - b0);
    float w0 = 1.f / (1.f + e1v);
    float w1 = e1v / (1.f + e1v);
    float o[4] = {0.f, 0.f, 0.f, 0.f};
    o[i0] = w0; o[i1] = w1;
    float* g = gw + t * 4;
    g[0] = o[0]; g[1] = o[1]; g[2] = o[2]; g[3] = o[3];
  }
}

// ---------------- gating + fp32->bf16 conversion fused (same math/order) ----
__global__ __launch_bounds__(64) void gate_conv_kernel(
    const float* __restrict__ x, const float* __restrict__ Wg,
    float* __restrict__ gw, unsigned short* __restrict__ xb) {
  int t = blockIdx.x;
  int lane = threadIdx.x;
  const float* xr = x + (size_t)t * H_;
  unsigned short* xbr = xb + (size_t)t * H_;
  float a0 = 0.f, a1 = 0.f, a2 = 0.f, a3 = 0.f;
  for (int h = lane; h < H_; h += 64) {
    float xv = xr[h];
    xbr[h] = f2bf(xv);
    const float* wr = Wg + h * 4;
    a0 += xv * wr[0]; a1 += xv * wr[1]; a2 += xv * wr[2]; a3 += xv * wr[3];
  }
  for (int off = 32; off > 0; off >>= 1) {
    a0 += __shfl_down(a0, off);
    a1 += __shfl_down(a1, off);
    a2 += __shfl_down(a2, off);
    a3 += __shfl_down(a3, off);
  }
  if (lane == 0) {
    float v[4] = {a0, a1, a2, a3};
    int i0 = 0; float b0 = v[0];
    for (int e = 1; e < 4; ++e) if (v[e] > b0) { b0 = v[e]; i0 = e; }
    int i1 = -1; float b1 = -INFINITY;
    for (int e = 0; e < 4; ++e) { if (e == i0) continue; if (v[e] > b1) { b1 = v[e]; i1 = e; } }
    float e1v = expf(b1 - b0);
    float w0 = 1.f / (1.f + e1v);
    float w1 = e1v / (1.f + e1v);
    float o[4] = {0.f, 0.f, 0.f, 0.f};
    o[i0] = w0; o[i1] = w1;
    float* g = gw + t * 4;
    g[0] = o[0]; g[1] = o[1]; g[2] = o[2]; g[3] = o[3];
  }
}

// -------------------------------------------------------- fp32 -> bf16 ------
__global__ __launch_bounds__(256) void conv_kernel(
    const float* __restrict__ src, unsigned short* __restrict__ dst,
    int nsrc, int ldsrc) {
  int idx = blockIdx.x * 256 + threadIdx.x;
  int m = idx >> 10, c = idx & 1023;
  dst[idx] = (c < nsrc) ? f2bf(src[(size_t)m * ldsrc + c]) : (unsigned short)0;
}

// --------------------- weight transpose + bf16, 4 matrices in one launch ----
__global__ __launch_bounds__(256) void wtrans4_kernel(
    const float* __restrict__ s0, const float* __restrict__ s1,
    const float* __restrict__ s2, const float* __restrict__ s3,
    unsigned short* __restrict__ d0, unsigned short* __restrict__ d1,
    unsigned short* __restrict__ d2, unsigned short* __restrict__ d3, int pd) {
  __shared__ float tile[32][33];
  int z = blockIdx.z;
  const float* src = (z == 0) ? s0 : (z == 1) ? s1 : (z == 2) ? s2 : s3;
  unsigned short* dst = (z == 0) ? d0 : (z == 1) ? d1 : (z == 2) ? d2 : d3;
  int ksrc = (z < 3) ? 1024 : pd;
  int nsrc = (z < 3) ? pd : 1024;
  int ldsrc = (z < 3) ? pd : 1024;
  int k0 = blockIdx.x * 32, n0 = blockIdx.y * 32;
  int tx = threadIdx.x & 31, ty = threadIdx.x >> 5;
  for (int i = 0; i < 32; i += 8) {
    int k = k0 + ty + i, n = n0 + tx;
    tile[ty + i][tx] = (k < ksrc && n < nsrc) ? src[(size_t)k * ldsrc + n] : 0.f;
  }
  __syncthreads();
  for (int i = 0; i < 32; i += 8) {
    int n = n0 + ty + i, k = k0 + tx;
    dst[(size_t)n * 1024 + k] = f2bf(tile[tx][ty + i]);
  }
}

// ------------- weight transpose, ALL 16 matrices (4 experts) in one launch --
struct W16 {
  const float* src[16];
  unsigned short* dst[16];
  int pd[4];
};
__global__ __launch_bounds__(256) void wtrans16_kernel(W16 p) {
  __shared__ float tile[32][33];
  int z = blockIdx.z;
  int e = z >> 2, m = z & 3;
  const float* src = p.src[z];
  unsigned short* dst = p.dst[z];
  int pd = p.pd[e];
  int ksrc = (m < 3) ? 1024 : pd;
  int nsrc = (m < 3) ? pd : 1024;
  int ldsrc = (m < 3) ? pd : 1024;
  int k0 = blockIdx.x * 32, n0 = blockIdx.y * 32;
  int tx = threadIdx.x & 31, ty = threadIdx.x >> 5;
  for (int i = 0; i < 32; i += 8) {
    int k = k0 + ty + i, n = n0 + tx;
    tile[ty + i][tx] = (k < ksrc && n < nsrc) ? src[(size_t)k * ldsrc + n] : 0.f;
  }
  __syncthreads();
  for (int i = 0; i < 32; i += 8) {
    int n = n0 + ty + i, k = k0 + tx;
    dst[(size_t)n * 1024 + k] = f2bf(tile[tx][ty + i]);
  }
}

// ------------------------------------------------------- bf16 MFMA GEMM -----
// (fallback path only; BK=32)
__global__ __launch_bounds__(256) void gemm_mfma(
    const unsigned short* __restrict__ A, const unsigned short* __restrict__ Bt,
    const float* __restrict__ b0, const float* __restrict__ b1,
    const float* __restrict__ b2, void* __restrict__ Cv, int ldc,
    int nact, int elu_ncut, int out_bf16, int mode,
    const float* __restrict__ gw, int expert, int remap,
    int qs_ncut, float qscale) {
  constexpr int K = 1024;
  __shared__ __align__(16) unsigned short As[128 * 32];
  __shared__ __align__(16) unsigned short Bs[128 * 32];
  int tid = threadIdx.x, wave = tid >> 6, lane = tid & 63;
  int quad = lane >> 4, lrow = lane & 15;
  int rw = (wave >> 1) * 64, cw = (wave & 1) * 64;
  int m0 = blockIdx.y * 128, n0 = blockIdx.x * 128;
  int srow = wave * 32 + (lane >> 2);
  int scol = (lane & 3) * 8;
  const unsigned short* gA = A + (size_t)(m0 + srow) * K + scol;
  const unsigned short* gB = Bt + (size_t)(n0 + srow) * K + scol;
  unsigned short* lA = &As[wave * 1024];
  unsigned short* lB = &Bs[wave * 1024];
  f32x4 acc[4][4];
#pragma unroll
  for (int mt = 0; mt < 4; ++mt)
#pragma unroll
    for (int nt = 0; nt < 4; ++nt) acc[mt][nt] = (f32x4){0.f, 0.f, 0.f, 0.f};

  for (int k0 = 0; k0 < K; k0 += 32) {
    gld16(gA + k0, lA);
    gld16(gA + 16 * K + k0, lA + 512);
    gld16(gB + k0, lB);
    gld16(gB + 16 * K + k0, lB + 512);
    __syncthreads();
    bf16x8 af[4], bfr[4];
#pragma unroll
    for (int t = 0; t < 4; ++t) {
      af[t]  = *(const bf16x8*)&As[(rw + t * 16 + lrow) * 32 + quad * 8];
      bfr[t] = *(const bf16x8*)&Bs[(cw + t * 16 + lrow) * 32 + quad * 8];
    }
#pragma unroll
    for (int mt = 0; mt < 4; ++mt)
#pragma unroll
      for (int nt = 0; nt < 4; ++nt)
        acc[mt][nt] = __builtin_amdgcn_mfma_f32_16x16x32_bf16(
            af[mt], bfr[nt], acc[mt][nt], 0, 0, 0);
    __syncthreads();
  }
#pragma unroll
  for (int nt = 0; nt < 4; ++nt) {
    int n = n0 + cw + nt * 16 + lrow;
    int slice = n >> 10, noff = n & 1023;
    if (noff >= nact) continue;
    const float* bp = (slice == 0) ? b0 : (slice == 1) ? b1 : b2;
    float bias = bp[noff];
    bool do_elu = n < elu_ncut;
    bool do_qs = n < qs_ncut;
    int col = n;
    if (remap) {
      int head = (noff * 12337) >> 20;  // noff/85 for noff<1020
      col = slice * 1152 + head * 96 + (noff - head * 85);
    }
#pragma unroll
    for (int mt = 0; mt < 4; ++mt) {
      int mb = m0 + rw + mt * 16 + quad * 4;
#pragma unroll
      for (int r = 0; r < 4; ++r) {
        int m = mb + r;
        float val = acc[mt][nt][r] + bias;
        if (do_elu) val = (val > 0.f) ? val + 1.f : expf(val);
        if (do_qs) val *= qscale;
        size_t ci = (size_t)m * ldc + col;
        if (out_bf16) {
          ((unsigned short*)Cv)[ci] = f2bf(val);
        } else {
          float* C = (float*)Cv;
          if (mode == 0) C[ci] = val;
          else {
            float g = gw[m * 4 + expert];
            if (mode == 1) C[ci] = g * val;
            else           C[ci] += g * val;
          }
        }
      }
    }
  }
}

// ============== 256x256 counted-prefetch GEMM core (K=1024) =================
// R10: R9 minus the scheduling directives. R9 proved the swizzle (bank
// conflicts = 0) but its sched_barrier(0)/setprio pinning regressed to 452 TF
// — matching the documented m141 failure mode. Here the compiler schedules
// freely (m97 evidence: it emits fine-grained lgkmcnt itself):
//   STAGE(t+1 -> buf^1) issued first (counted prefetch, loads span the
//   64-MFMA window), then frag reads + MFMAs, then ONE __syncthreads.
// LDS swizzle (T2): logical (row,c) ushort at col c ^ ((row&7)<<3); realized
// by pre-swizzled GLOBAL source (gld16 writes linearly) + same XOR on ds_read
// (both-sides, rule #21). Accumulation K-ascending == old kernels =>
// bit-identical output; absmax is the canary.
__device__ __forceinline__ void stage_tile(
    const unsigned short* __restrict__ A, const unsigned short* __restrict__ Bt,
    int m0, int n0, int kbase, unsigned short* Abuf, unsigned short* Bbuf,
    int wave, int lane) {
#pragma unroll
  for (int j = 0; j < 2; ++j) {
    int t = j * 512 + wave * 64 + lane;      // 16B-slot id within half-tile
    int rl = t >> 3;                          // row 0..127 within half
    int c0 = ((t & 7) * 8) ^ ((rl & 7) << 3); // pre-swizzled source col
    int ldst = (j * 512 + wave * 64) * 8;     // wave-uniform LDS base (ushorts)
    gld16(A + (size_t)(m0 + rl) * 1024 + kbase + c0, Abuf + ldst);
    gld16(A + (size_t)(m0 + 128 + rl) * 1024 + kbase + c0, Abuf + 8192 + ldst);
    gld16(Bt + (size_t)(n0 + rl) * 1024 + kbase + c0, Bbuf + ldst);
    gld16(Bt + (size_t)(n0 + 128 + rl) * 1024 + kbase + c0, Bbuf + 8192 + ldst);
  }
}

__device__ __forceinline__ void gemm256_core(
    const unsigned short* __restrict__ A, const unsigned short* __restrict__ Bt,
    int m0, int n0, unsigned short* As, unsigned short* Bs,
    f32x4 (&acc)[8][4]) {
  int tid = threadIdx.x;
  int wave = tid >> 6, lane = tid & 63;
  int quad = lane >> 4, l15 = lane & 15;
  int wr = wave >> 2, wc = wave & 3;
#pragma unroll
  for (int mr = 0; mr < 8; ++mr)
#pragma unroll
    for (int nr = 0; nr < 4; ++nr) acc[mr][nr] = (f32x4){0.f, 0.f, 0.f, 0.f};
  stage_tile(A, Bt, m0, n0, 0, As, Bs, wave, lane);
  __syncthreads();
  int cur = 0;
  for (int t = 0; t < 16; ++t) {
    if (t + 1 < 16)
      stage_tile(A, Bt, m0, n0, (t + 1) * 64, As + (cur ^ 1) * 16384,
                 Bs + (cur ^ 1) * 16384, wave, lane);
    const unsigned short* Ar = As + cur * 16384;
    const unsigned short* Br = Bs + cur * 16384;
#pragma unroll
    for (int ks = 0; ks < 2; ++ks) {
      int c = ks * 32 + quad * 8;
      bf16x8 af[8], bfr[4];
#pragma unroll
      for (int i = 0; i < 4; ++i) {
        int row = wc * 64 + i * 16 + l15;
        bfr[i] = *(const bf16x8*)&Br[row * 64 + (c ^ ((row & 7) << 3))];
      }
#pragma unroll
      for (int i = 0; i < 8; ++i) {
        int row = wr * 128 + i * 16 + l15;
        af[i] = *(const bf16x8*)&Ar[row * 64 + (c ^ ((row & 7) << 3))];
      }
#pragma unroll
      for (int mr = 0; mr < 8; ++mr)
#pragma unroll
        for (int nr = 0; nr < 4; ++nr)
          acc[mr][nr] = __builtin_amdgcn_mfma_f32_16x16x32_bf16(
              af[mr], bfr[nr], acc[mr][nr], 0, 0, 0);
    }
    __syncthreads();
    cur ^= 1;
  }
}

// --------------------------- merged QKV projection GEMM, z=expert -----------
struct QkvP {
  const unsigned short* Bt[4];
  const float* bq[4];
  const float* bk[4];
  const float* bv[4];
  unsigned short* C[4];
  int ldc[4];
  int nact[4];
  int elu_ncut[4];
  int remap[4];
  int qs_ncut[4];
  float qscale[4];
};
__global__ __launch_bounds__(512, 1) void gemm_qkv4_v2(
    const unsigned short* __restrict__ A, QkvP p) {
  __shared__ __align__(16) unsigned short As[2 * 256 * 64];
  __shared__ __align__(16) unsigned short Bs[2 * 256 * 64];
  int e = blockIdx.z;
  // XCD-aware bijective swizzle within expert slice (192 blocks, 192%8==0)
  int flat = blockIdx.y * 12 + blockIdx.x;
  int swz = (flat & 7) * 24 + (flat >> 3);
  int m0 = (swz / 12) * 256, n0 = (swz % 12) * 256;
  f32x4 acc[8][4];
  gemm256_core(A, p.Bt[e], m0, n0, As, Bs, acc);
  int nact = p.nact[e], elu_ncut = p.elu_ncut[e], remap = p.remap[e];
  int qs_ncut = p.qs_ncut[e], ldc = p.ldc[e];
  float qscale = p.qscale[e];
  unsigned short* Cv = p.C[e];
  int tid = threadIdx.x, wave = tid >> 6, lane = tid & 63;
  int quad = lane >> 4, l15 = lane & 15;
  int wr = wave >> 2, wc = wave & 3;
#pragma unroll
  for (int nr = 0; nr < 4; ++nr) {
    int n = n0 + wc * 64 + nr * 16 + l15;
    int slice = n >> 10, noff = n & 1023;
    if (noff >= nact) continue;
    const float* bp = (slice == 0) ? p.bq[e] : (slice == 1) ? p.bk[e] : p.bv[e];
    float bias = bp[noff];
    bool do_elu = n < elu_ncut;
    bool do_qs = n < qs_ncut;
    int col = n;
    if (remap) {
      int head = (noff * 12337) >> 20;  // noff/85 for noff<1020
      col = slice * 1152 + head * 96 + (noff - head * 85);
    }
#pragma unroll
    for (int mr = 0; mr < 8; ++mr) {
      int mb = m0 + wr * 128 + mr * 16 + quad * 4;
#pragma unroll
      for (int r = 0; r < 4; ++r) {
        int m = mb + r;
        float val = acc[mr][nr][r] + bias;
        if (do_elu) val = (val > 0.f) ? val + 1.f : expf(val);
        if (do_qs) val *= qscale;
        Cv[(size_t)m * ldc + col] = f2bf(val);
      }
    }
  }
}

// ------------------------------------- merged output projection, z=expert ---
struct OutP {
  const unsigned short* A[4];
  const unsigned short* B[4];
  const float* bias[4];
};
__global__ __launch_bounds__(512, 1) void gemm_out4_v2(
    OutP p, const float* __restrict__ gw, float* __restrict__ part) {
  __shared__ __align__(16) unsigned short As[2 * 256 * 64];
  __shared__ __align__(16) unsigned short Bs[2 * 256 * 64];
  int e = blockIdx.z;
  int flat = blockIdx.y * 4 + blockIdx.x;  // 64 blocks, 64%8==0
  int swz = (flat & 7) * 8 + (flat >> 3);
  int m0 = (swz / 4) * 256, n0 = (swz % 4) * 256;
  f32x4 acc[8][4];
  gemm256_core(p.A[e], p.B[e], m0, n0, As, Bs, acc);
  const float* bp = p.bias[e];
  float* C = part + (size_t)e * (4096ull * 1024ull);
  int tid = threadIdx.x, wave = tid >> 6, lane = tid & 63;
  int quad = lane >> 4, l15 = lane & 15;
  int wr = wave >> 2, wc = wave & 3;
#pragma unroll
  for (int nr = 0; nr < 4; ++nr) {
    int n = n0 + wc * 64 + nr * 16 + l15;
    float bias = bp[n];
#pragma unroll
    for (int mr = 0; mr < 8; ++mr) {
      int mb = m0 + wr * 128 + mr * 16 + quad * 4;
#pragma unroll
      for (int r = 0; r < 4; ++r) {
        int m = mb + r;
        float g = gw[m * 4 + e];
        C[(size_t)m * 1024 + n] = g * (acc[mr][nr][r] + bias);
      }
    }
  }
}

// part[e] summed in expert order -> identical rounding to old mode1/mode2 chain
__global__ __launch_bounds__(256) void reduce4(
    const float* __restrict__ part, float* __restrict__ out) {
  constexpr size_t N = 4096ull * 1024ull;
  size_t idx = ((size_t)blockIdx.x * 256 + threadIdx.x) * 4;
  f32x4 a0 = *(const f32x4*)(part + idx);
  f32x4 a1 = *(const f32x4*)(part + idx + N);
  f32x4 a2 = *(const f32x4*)(part + idx + 2 * N);
  f32x4 a3 = *(const f32x4*)(part + idx + 3 * N);
  f32x4 s;
#pragma unroll
  for (int j = 0; j < 4; ++j) {
    float t = a0[j];
    t += a1[j]; t += a2[j]; t += a3[j];
    s[j] = t;
  }
  *(f32x4*)(out + idx) = s;
}

// ----- zero never-written pad columns (e1 head-pad 85..95, aob1 1020..1023) -
__global__ __launch_bounds__(256) void padzero(
    unsigned short* __restrict__ qkv1, unsigned short* __restrict__ aob1) {
  int idx = blockIdx.x * 256 + threadIdx.x;  // grid covers 4096*396 exactly
  int m = idx / 396, r = idx % 396;
  int slice = r / 132, r2 = r % 132;
  int head = r2 / 11, c = 85 + r2 % 11;
  qkv1[(size_t)m * 3456 + slice * 1152 + head * 96 + c] = 0;
  if (idx < 4096 * 4) {
    int mm = idx >> 2, cc = 1020 + (idx & 3);
    aob1[(size_t)mm * 1024 + cc] = 0;
  }
}

// --------------------------------------------- MFMA flash attention v6 ------
// 512 thr, QT=256, double-buffered Ks/Vt, one barrier per KT-iteration.
template <int HD, bool LOCAL>
__device__ __forceinline__ void attn_body(
    char* smem,
    const unsigned short* __restrict__ q, const unsigned short* __restrict__ k,
    const unsigned short* __restrict__ v, const int* __restrict__ amask,
    unsigned short* __restrict__ ao, int ldq, int h) {
  constexpr int HDP = (HD + 31) & ~31;  // 128 or 96
  constexpr int DCH = HDP / 32;         // 4 or 3
  constexpr int NDT = HDP / 16;         // 8 or 6
  constexpr int NCH = HDP / 8;          // 16 or 12
  constexpr int QT = 256, KT = 64;
  constexpr int KLD = HDP + 8;
  constexpr int VLD = KT + 4;
  constexpr int W2 = 32;
  constexpr int KSZ = KT * KLD;   // ushorts per K buffer
  constexpr int VSZ = HDP * VLD;  // halves per V buffer
  unsigned short* Ks = (unsigned short*)smem;              // [2][KSZ]
  _Float16* Vt = (_Float16*)(smem + 2 * KSZ * 2);          // [2][VSZ]
  unsigned long long* amq =
      (unsigned long long*)(smem + 2 * KSZ * 2 + 2 * VSZ * 2);
  int tid = threadIdx.x, wave = tid >> 6, lane = tid & 63;
  int quad = lane >> 4, l15 = lane & 15;
  int q0 = blockIdx.x * QT, b = blockIdx.z;
  size_t baseq = ((size_t)b * S_) * ldq + (size_t)h * HDP;
  size_t baseo = ((size_t)b * S_) * H_ + (size_t)h * HD;

  {
    unsigned long long bb0 = __ballot(amask[b * S_ + wave * 128 + lane] != 0);
    unsigned long long bb1 = __ballot(amask[b * S_ + wave * 128 + 64 + lane] != 0);
    if (lane == 0) { amq[wave * 2] = bb0; amq[wave * 2 + 1] = bb1; }
  }

  int qrow[2];
  bf16x8 qf[2][DCH];
#pragma unroll
  for (int g = 0; g < 2; ++g) {
    qrow[g] = q0 + wave * 32 + g * 16 + l15;
#pragma unroll
    for (int c = 0; c < DCH; ++c)
#pragma unroll
      for (int j = 0; j < 8; ++j) {
        int d = c * 32 + quad * 8 + j;
        qf[g][c][j] =
            (d < HD) ? (short)q[baseq + (size_t)qrow[g] * ldq + d] : (short)0;
      }
  }

  int jlo = 0, jhi = S_;
  if (LOCAL) {
    jlo = q0 - W2; if (jlo < 0) jlo = 0; jlo &= ~(KT - 1);
    jhi = q0 + QT + W2; if (jhi > S_) jhi = S_;
  }

  int skey = tid & 63, sc8a = tid >> 6, sc8b = 8 + (tid >> 6);
  bool sactb = sc8b < NCH;
  const unsigned short* kg = k + baseq + (size_t)skey * ldq;
  const unsigned short* vg = v + baseq + (size_t)skey * ldq;
  bf16x8 kra = {}, krb = {}, vra = {}, vrb = {};
  {
    size_t o = (size_t)jlo * ldq;
    kra = *(const bf16x8*)(kg + o + sc8a * 8);
    vra = *(const bf16x8*)(vg + o + sc8a * 8);
    if (sactb) {
      krb = *(const bf16x8*)(kg + o + sc8b * 8);
      vrb = *(const bf16x8*)(vg + o + sc8b * 8);
    }
  }

  // prologue: stage tile jlo into buffer 0
  {
    *(bf16x8*)&Ks[skey * KLD + sc8a * 8] = kra;
#pragma unroll
    for (int j = 0; j < 8; ++j)
      Vt[(sc8a * 8 + j) * VLD + skey] = (_Float16)bf2f((unsigned short)vra[j]);
    if (sactb) {
      *(bf16x8*)&Ks[skey * KLD + sc8b * 8] = krb;
#pragma unroll
      for (int j = 0; j < 8; ++j)
        Vt[(sc8b * 8 + j) * VLD + skey] = (_Float16)bf2f((unsigned short)vrb[j]);
    }
  }
  int cur = 0;
  __syncthreads();

  float m_run[2] = {-1e30f, -1e30f}, l_run[2] = {0.f, 0.f};
  f32x4 accd[2][NDT];
#pragma unroll
  for (int g = 0; g < 2; ++g)
#pragma unroll
    for (int dt = 0; dt < NDT; ++dt) accd[g][dt] = (f32x4){0.f, 0.f, 0.f, 0.f};

  for (int j0 = jlo; j0 < jhi; j0 += KT) {
    int jn = j0 + KT;
    if (jn < jhi) {
      size_t o = (size_t)jn * ldq;
      kra = *(const bf16x8*)(kg + o + sc8a * 8);
      vra = *(const bf16x8*)(vg + o + sc8a * 8);
      if (sactb) {
        krb = *(const bf16x8*)(kg + o + sc8b * 8);
        vrb = *(const bf16x8*)(vg + o + sc8b * 8);
      }
    }
    const unsigned short* KsR = Ks + cur * KSZ;
    const _Float16* VtR = Vt + cur * VSZ;
    f32x4 sf[2][4];
#pragma unroll
    for (int kt = 0; kt < 4; ++kt) {
      sf[0][kt] = (f32x4){0.f, 0.f, 0.f, 0.f};
      sf[1][kt] = (f32x4){0.f, 0.f, 0.f, 0.f};
#pragma unroll
      for (int c = 0; c < DCH; ++c) {
        bf16x8 kf = *(const bf16x8*)&KsR[(kt * 16 + l15) * KLD + c * 32 + quad * 8];
        sf[0][kt] = __builtin_amdgcn_mfma_f32_16x16x32_bf16(kf, qf[0][c], sf[0][kt], 0, 0, 0);
        sf[1][kt] = __builtin_amdgcn_mfma_f32_16x16x32_bf16(kf, qf[1][c], sf[1][kt], 0, 0, 0);
      }
    }
    unsigned long long mb = amq[j0 >> 6];
    unsigned mw[2] = {(unsigned)mb, (unsigned)(mb >> 32)};
    float pvv[2][4][4];
    float mx[2] = {-1e30f, -1e30f};
#pragma unroll
    for (int kt = 0; kt < 4; ++kt) {
      unsigned word = mw[kt >> 1];
      int sh = (kt & 1) * 16 + quad * 4;
#pragma unroll
      for (int r = 0; r < 4; ++r) {
        bool okm = (word >> (sh + r)) & 1;
#pragma unroll
        for (int g = 0; g < 2; ++g) {
          bool ok = okm;
          if (LOCAL) {
            int dj = (j0 + kt * 16 + quad * 4 + r) - qrow[g];
            ok = ok && (dj <= W2) && (dj >= -W2);
          }
          float s = ok ? sf[g][kt][r] : -1e30f;
          pvv[g][kt][r] = s;
          mx[g] = fmaxf(mx[g], s);
        }
      }
    }
    half4 pf[2][4];
    float aR[2][4];
#pragma unroll
    for (int g = 0; g < 2; ++g) {
      float mxg = fmaxf(mx[g], __shfl_xor(mx[g], 16));
      mxg = fmaxf(mxg, __shfl_xor(mxg, 32));
      float m_new = fmaxf(m_run[g], mxg);
      float psum = 0.f;
#pragma unroll
      for (int kt = 0; kt < 4; ++kt)
#pragma unroll
        for (int r = 0; r < 4; ++r) {
          float s = pvv[g][kt][r];
          float p = (s > -1e29f) ? __builtin_amdgcn_exp2f(s - m_new) : 0.f;
          pvv[g][kt][r] = p;
          psum += p;
        }
      psum += __shfl_xor(psum, 16);
      psum += __shfl_xor(psum, 32);
      float alpha = __builtin_amdgcn_exp2f(m_run[g] - m_new);
      m_run[g] = m_new;
      l_run[g] = l_run[g] * alpha + psum;
#pragma unroll
      for (int r = 0; r < 4; ++r)
        aR[g][r] = __shfl(alpha, (lane & 48) | (quad * 4 + r));
#pragma unroll
      for (int dt = 0; dt < NDT; ++dt)
#pragma unroll
        for (int r = 0; r < 4; ++r) accd[g][dt][r] *= aR[g][r];
#pragma unroll
      for (int kt = 0; kt < 4; ++kt)
#pragma unroll
        for (int r = 0; r < 4; ++r) pf[g][kt][r] = (_Float16)pvv[g][kt][r];
    }
    if (jn < jhi) {
      unsigned short* KsW = Ks + (cur ^ 1) * KSZ;
      _Float16* VtW = Vt + (cur ^ 1) * VSZ;
      *(bf16x8*)&KsW[skey * KLD + sc8a * 8] = kra;
#pragma unroll
      for (int j = 0; j < 8; ++j)
        VtW[(sc8a * 8 + j) * VLD + skey] = (_Float16)bf2f((unsigned short)vra[j]);
      if (sactb) {
        *(bf16x8*)&KsW[skey * KLD + sc8b * 8] = krb;
#pragma unroll
        for (int j = 0; j < 8; ++j)
          VtW[(sc8b * 8 + j) * VLD + skey] = (_Float16)bf2f((unsigned short)vrb[j]);
      }
    }
#pragma unroll
    for (int dt = 0; dt < NDT; ++dt)
#pragma unroll
      for (int kt = 0; kt < 4; ++kt) {
        half4 vf = *(const half4*)&VtR[(dt * 16 + l15) * VLD + kt * 16 + quad * 4];
        accd[0][dt] = __builtin_amdgcn_mfma_f32_16x16x16f16(pf[0][kt], vf, accd[0][dt], 0, 0, 0);
        accd[1][dt] = __builtin_amdgcn_mfma_f32_16x16x16f16(pf[1][kt], vf, accd[1][dt], 0, 0, 0);
      }
    __syncthreads();
    cur ^= 1;
  }
#pragma unroll
  for (int g = 0; g < 2; ++g) {
    float linv = (l_run[g] > 0.f) ? 1.f / l_run[g] : 0.f;
    float lR[4];
#pragma unroll
    for (int r = 0; r < 4; ++r)
      lR[r] = __shfl(linv, (lane & 48) | (quad * 4 + r));
#pragma unroll
    for (int dt = 0; dt < NDT; ++dt) {
      int d = dt * 16 + l15;
      if (d >= HD) continue;
#pragma unroll
      for (int r = 0; r < 4; ++r) {
        int row = q0 + wave * 32 + g * 16 + quad * 4 + r;
        ao[baseo + (size_t)row * H_ + d] = f2bf(accd[g][dt][r] * lR[r]);
      }
    }
  }
}

template <int HD, bool LOCAL>
__global__ __launch_bounds__(512) void attn_mfma3(
    const unsigned short* __restrict__ q, const unsigned short* __restrict__ k,
    const unsigned short* __restrict__ v, const int* __restrict__ amask,
    unsigned short* __restrict__ ao, int ldq) {
  constexpr int HDP = (HD + 31) & ~31;
  __shared__ __align__(16) char smem[2 * 64 * (HDP + 8) * 2 + 2 * HDP * 68 * 2 + 128];
  attn_body<HD, LOCAL>(smem, q, k, v, amask, ao, ldq, blockIdx.y);
}

// ------------------------------------------------------ linear attention ----
#define NSPLIT 4
__device__ __forceinline__ void linkv_body(
    char* smemi, const unsigned short* __restrict__ k,
    const unsigned short* __restrict__ v, float* __restrict__ kvp,
    float* __restrict__ ksump, int ld, int h, int b, int split, int tid) {
  constexpr int HD = 128;
  constexpr int TLD = 34;
  unsigned short* Kt = (unsigned short*)smemi;           // 8704 B
  unsigned short* Vt = Kt + HD * TLD;                    // 8704 B
  int bh = b * 8 + h;
  int wave = tid >> 6, lane = tid & 63;
  int quad = lane >> 4, l15 = lane & 15;
  int rw = (wave >> 1) * 64, cw = (wave & 1) * 64;
  size_t base = ((size_t)b * S_) * ld + (size_t)h * HD;
  int s_begin = split * (S_ / NSPLIT);

  f32x4 acc[4][4];
#pragma unroll
  for (int mt = 0; mt < 4; ++mt)
#pragma unroll
    for (int nt = 0; nt < 4; ++nt) acc[mt][nt] = (f32x4){0.f, 0.f, 0.f, 0.f};
  float ksacc = 0.f;
  int myd = tid & 127, half = tid >> 7;

  for (int c0 = 0; c0 < S_ / NSPLIT; c0 += 32) {
    for (int idx = tid; idx < 32 * HD; idx += 256) {
      int d = idx & 127, s = idx >> 7;
      size_t g = base + (size_t)(s_begin + c0 + s) * ld + d;
      Kt[d * TLD + s] = k[g];
      Vt[d * TLD + s] = v[g];
    }
    __syncthreads();
    bf16x8 af[4], bf[4];
#pragma unroll
    for (int t = 0; t < 4; ++t) {
      af[t] = *(const bf16x8*)&Vt[(rw + t * 16 + l15) * TLD + quad * 8];
      bf[t] = *(const bf16x8*)&Kt[(cw + t * 16 + l15) * TLD + quad * 8];
    }
#pragma unroll
    for (int mt = 0; mt < 4; ++mt)
#pragma unroll
      for (int nt = 0; nt < 4; ++nt)
        acc[mt][nt] = __builtin_amdgcn_mfma_f32_16x16x32_bf16(
            af[mt], bf[nt], acc[mt][nt], 0, 0, 0);
#pragma unroll
    for (int s = 0; s < 16; ++s)
      ksacc += bf2f(Kt[myd * TLD + half * 16 + s]);
    __syncthreads();
  }
  float* red = (float*)Kt;
  if (half == 1) red[myd] = ksacc;
  __syncthreads();
  if (half == 0)
    ksump[((size_t)split * 32 + bh) * HD + myd] = ksacc + red[myd];
  float* kvo = kvp + ((size_t)split * 32 + bh) * (HD * HD);
#pragma unroll
  for (int mt = 0; mt < 4; ++mt)
#pragma unroll
    for (int nt = 0; nt < 4; ++nt) {
      int dk = cw + nt * 16 + l15;
#pragma unroll
      for (int r = 0; r < 4; ++r) {
        int dv = rw + mt * 16 + quad * 4 + r;
        kvo[(size_t)dv * HD + dk] = acc[mt][nt][r];
      }
    }
}

__global__ __launch_bounds__(256) void linkv_mfma(
    const unsigned short* __restrict__ k, const unsigned short* __restrict__ v,
    float* __restrict__ kvp, float* __restrict__ ksump, int ld) {
  __shared__ __align__(16) char smemi[17408];
  linkv_body(smemi, k, v, kvp, ksump, ld, blockIdx.x, blockIdx.y, blockIdx.z,
             threadIdx.x);
}

// one launch: e0 (y<8) + e1 (y<20) + e3 local (y<28) + linkv e2 (y<32,
// two 256-thr instances per block). Grid (4, 32, 4) = 512 blocks = 2/CU.
__global__ __launch_bounds__(512) void attn_mega(
    const unsigned short* __restrict__ qkv0,
    const unsigned short* __restrict__ qkv1,
    const unsigned short* __restrict__ qkv2,
    const unsigned short* __restrict__ qkv3, const int* __restrict__ amask,
    unsigned short* __restrict__ ao0, unsigned short* __restrict__ ao1,
    unsigned short* __restrict__ ao3,
    float* __restrict__ kvp, float* __restrict__ ksump) {
  __shared__ __align__(16) char smem[69760];
  int y = blockIdx.y;
  if (y < 8)
    attn_body<128, false>(smem, qkv0, qkv0 + 1024, qkv0 + 2048, amask, ao0,
                          3072, y);
  else if (y < 20)
    attn_body<85, false>(smem, qkv1, qkv1 + 1152, qkv1 + 2304, amask, ao1,
                         3456, y - 8);
  else if (y < 28)
    attn_body<128, true>(smem, qkv3, qkv3 + 1024, qkv3 + 2048, amask, ao3,
                         3072, y - 20);
  else {
    int sub = threadIdx.x >> 8, stid = threadIdx.x & 255;
    int idx = (y - 28) * 8 + blockIdx.x * 2 + sub;  // 32 combos per b
    linkv_body(smem + sub * 17408, qkv2 + 1024, qkv2 + 2048, kvp, ksump, 3072,
               idx & 7, blockIdx.z, idx >> 3, stid);
  }
}

__global__ __launch_bounds__(256) void linkv_reduce(
    const float* __restrict__ kvp, const float* __restrict__ ksump,
    unsigned short* __restrict__ kvb, float* __restrict__ ksum) {
  int idx = blockIdx.x * 256 + threadIdx.x;
  float s = 0.f;
#pragma unroll
  for (int p = 0; p < NSPLIT; ++p) s += kvp[(size_t)p * (32 * 128 * 128) + idx];
  kvb[idx] = f2bf(s);
  if (idx < 32 * 128) {
    float t = 0.f;
#pragma unroll
    for (int p = 0; p < NSPLIT; ++p) t += ksump[(size_t)p * (32 * 128) + idx];
    ksum[idx] = t;
  }
}

__global__ __launch_bounds__(256) void linattn_mfma(
    const unsigned short* __restrict__ q, const unsigned short* __restrict__ kvT,
    const float* __restrict__ ksum, unsigned short* __restrict__ ao, int ldq) {
  constexpr int KLD = 136;
  __shared__ __align__(16) unsigned short Ks[128 * KLD];
  __shared__ float ksL[128];
  int tid = threadIdx.x, wave = tid >> 6, lane = tid & 63;
  int quad = lane >> 4, l15 = lane & 15;
  int rw = (wave >> 1) * 64, cw = (wave & 1) * 64;
  int q0 = blockIdx.x * 128, h = blockIdx.y, b = blockIdx.z;
  int bh = b * 8 + h;
  size_t baseq = ((size_t)b * S_) * ldq + (size_t)h * 128;
  size_t baseo = ((size_t)b * S_) * H_ + (size_t)h * 128;
  const unsigned short* kvg = kvT + (size_t)bh * (128 * 128);
  for (int idx = tid; idx < 128 * 16; idx += 256) {
    int e = idx >> 4, c = idx & 15;
    *(bf16x8*)&Ks[e * KLD + c * 8] = *(const bf16x8*)&kvg[e * 128 + c * 8];
  }
  if (tid < 128) ksL[tid] = ksum[(size_t)bh * 128 + tid];
  bf16x8 qf[4][4];
#pragma unroll
  for (int mt = 0; mt < 4; ++mt) {
    const unsigned short* qr = q + baseq + (size_t)(q0 + rw + mt * 16 + l15) * ldq;
#pragma unroll
    for (int kc = 0; kc < 4; ++kc)
      qf[mt][kc] = *(const bf16x8*)&qr[kc * 32 + quad * 8];
  }
  __syncthreads();
  f32x4 acc[4][4];
#pragma unroll
  for (int mt = 0; mt < 4; ++mt)
#pragma unroll
    for (int nt = 0; nt < 4; ++nt) acc[mt][nt] = (f32x4){0.f, 0.f, 0.f, 0.f};
#pragma unroll
  for (int kc = 0; kc < 4; ++kc) {
    bf16x8 bf[4];
#pragma unroll
    for (int nt = 0; nt < 4; ++nt)
      bf[nt] = *(const bf16x8*)&Ks[(cw + nt * 16 + l15) * KLD + kc * 32 + quad * 8];
#pragma unroll
    for (int mt = 0; mt < 4; ++mt)
#pragma unroll
      for (int nt = 0; nt < 4; ++nt)
        acc[mt][nt] = __builtin_amdgcn_mfma_f32_16x16x32_bf16(
            qf[mt][kc], bf[nt], acc[mt][nt], 0, 0, 0);
  }
  float den[4];
#pragma unroll
  for (int mt = 0; mt < 4; ++mt) {
    float s = 0.f;
#pragma unroll
    for (int kc = 0; kc < 4; ++kc)
#pragma unroll
      for (int j = 0; j < 8; ++j)
        s += bf2f((unsigned short)qf[mt][kc][j]) * ksL[kc * 32 + quad * 8 + j];
    s += __shfl_xor(s, 16);
    s += __shfl_xor(s, 32);
    den[mt] = s;
  }
#pragma unroll
  for (int mt = 0; mt < 4; ++mt)
#pragma unroll
    for (int r = 0; r < 4; ++r) {
      float dv = __shfl(den[mt], (lane & 48) | (quad * 4 + r));
      float inv = 1.f / (dv + 1e-6f);
      int row = q0 + rw + mt * 16 + quad * 4 + r;
#pragma unroll
      for (int nt = 0; nt < 4; ++nt) {
        int col = cw + nt * 16 + l15;
        ao[baseo + (size_t)row * H_ + col] = f2bf(acc[mt][nt][r] * inv);
      }
    }
}

// ---------------------------------------------------------------- launch ----
extern "C" void kernel_launch(void* const* d_in, const int* in_sizes, int n_in,
                              void* d_out, int out_size, void* d_ws, size_t ws_size,
                              hipStream_t stream) {
  const float* x = (const float*)d_in[0];
  const float* Wg = (const float*)d_in[1];
  const int* amask = (const int*)d_in[34];
  float* out = (float*)d_out;
  char* ws = (char*)d_ws;
  const size_t MiB = 1ull << 20;
  const int nhs[4] = {8, 12, 8, 8};
  const float LOG2E = 1.4426950408889634f;

  if (ws_size >= 157 * MiB) {
    // ---- merged schedule. Aliasing plan (stream-ordered live ranges):
    //   kvp    @ 4 MiB  (8 MiB)  over xb     — xb dead after gemm_qkv4;
    //          attn_mega's linkv instances write kvp (after gemm_qkv4 ✓)
    //   ksump  @ 12 MiB (64 KB)
    //   qkvT4  @ 125 MiB (24 MiB) over aobE[0..2] — dead after gemm_qkv4;
    //          padzero runs AFTER gemm_qkv4; attn rewrites aobE afterwards.
    //   part   @ 26 MiB (64 MiB) over qkvE[0..2] — dead after attn/linattn.
    float* gw = (float*)ws;                                  // 64 KB
    float* ksum = (float*)(ws + (64ull << 10));              // 16 KB
    unsigned short* kvb = (unsigned short*)(ws + 1 * MiB);   // 1 MiB
    unsigned short* xb = (unsigned short*)(ws + 4 * MiB);    // 8 MiB
    float* kvp = (float*)(ws + 4 * MiB);                     // 8 MiB (alias xb)
    float* ksump = (float*)(ws + 12 * MiB);                  // 64 KB
    unsigned short* woT[4];
    for (int e = 0; e < 4; ++e)
      woT[e] = (unsigned short*)(ws + (18 + 2 * e) * MiB);   // 8 MiB
    const size_t qkvOff[4] = {26 * MiB, 50 * MiB, 77 * MiB, 101 * MiB};
    unsigned short* qkvE[4];
    for (int e = 0; e < 4; ++e) qkvE[e] = (unsigned short*)(ws + qkvOff[e]);
    float* part = (float*)(ws + 26 * MiB);                   // 64 MiB (alias qkvE)
    unsigned short* aobE[4];
    for (int e = 0; e < 4; ++e)
      aobE[e] = (unsigned short*)(ws + (125 + 8 * e) * MiB); // 32 MiB total
    unsigned short* qkvT4 = (unsigned short*)(ws + 125 * MiB); // 24 MiB (alias)

    gate_conv_kernel<<<4096, 64, 0, stream>>>(x, Wg, gw, xb);

    // all 16 weight transposes in one launch
    W16 w;
    for (int e = 0; e < 4; ++e) {
      w.pd[e] = nhs[e] * (H_ / nhs[e]);
      for (int m = 0; m < 3; ++m) {
        w.src[e * 4 + m] = (const float*)d_in[2 + 8 * e + 2 * m];  // Wq,Wk,Wv
        w.dst[e * 4 + m] = qkvT4 + (size_t)(e * 3 + m) * (1 << 20);
      }
      w.src[e * 4 + 3] = (const float*)d_in[2 + 8 * e + 6];        // Wo
      w.dst[e * 4 + 3] = woT[e];
    }
    wtrans16_kernel<<<dim3(32, 32, 16), 256, 0, stream>>>(w);

    // all 4 QKV projections in one launch (256² counted-prefetch, free sched)
    QkvP qp;
    for (int e = 0; e < 4; ++e) {
      int hd = H_ / nhs[e];
      int pd = nhs[e] * hd;
      qp.Bt[e] = qkvT4 + (size_t)(e * 3) * (1 << 20);
      qp.bq[e] = (const float*)d_in[2 + 8 * e + 1];
      qp.bk[e] = (const float*)d_in[2 + 8 * e + 3];
      qp.bv[e] = (const float*)d_in[2 + 8 * e + 5];
      qp.C[e] = qkvE[e];
      qp.ldc[e] = (e == 1) ? 3456 : 3072;
      qp.nact[e] = (pd == 1020) ? 1020 : 1024;
      qp.elu_ncut[e] = (e == 2) ? 2048 : 0;
      qp.remap[e] = (e == 1) ? 1 : 0;
      qp.qs_ncut[e] = (e == 2) ? 0 : 1024;
      qp.qscale[e] = LOG2E / sqrtf((float)hd);
    }
    gemm_qkv4_v2<<<dim3(12, 16, 4), 512, 0, stream>>>(xb, qp);

    // zero pad cols AFTER qkvT4 (aliasing aobE) is dead
    padzero<<<6336, 256, 0, stream>>>(qkvE[1], aobE[1]);

    // merged attention + linkv (kvp clobbers xb — dead now)
    attn_mega<<<dim3(S_ / 256, 32, B_), 512, 0, stream>>>(
        qkvE[0], qkvE[1], qkvE[2], qkvE[3], amask, aobE[0], aobE[1], aobE[3],
        kvp, ksump);

    linkv_reduce<<<(32 * 128 * 128) / 256, 256, 0, stream>>>(kvp, ksump, kvb, ksum);
    linattn_mfma<<<dim3(S_ / 128, 8, B_), 256, 0, stream>>>(
        qkvE[2], kvb, ksum, aobE[2], 3072);

    OutP p;
    for (int e = 0; e < 4; ++e) {
      p.A[e] = aobE[e];
      p.B[e] = woT[e];
      p.bias[e] = (const float*)d_in[2 + 8 * e + 7];
    }
    gemm_out4_v2<<<dim3(4, 16, 4), 512, 0, stream>>>(p, gw, part);
    reduce4<<<4096, 256, 0, stream>>>(part, out);
    return;
  }

  // ---- fallback: original sequential schedule (74 MiB workspace) ----
  float* gw            = (float*)(ws + 0);
  unsigned short* kvb  = (unsigned short*)(ws + (1ull << 20));
  float* ksum          = (float*)(ws + (3ull << 20) + (1ull << 19));
  unsigned short* xb   = (unsigned short*)(ws + (4ull << 20));
  unsigned short* qkvT = (unsigned short*)(ws + (12ull << 20));
  unsigned short* woT  = (unsigned short*)(ws + (18ull << 20));
  unsigned short* qkv  = (unsigned short*)(ws + (20ull << 20));
  unsigned short* aob  = (unsigned short*)(ws + (49ull << 20));
  float* kvp           = (float*)(ws + (57ull << 20));
  float* ksump         = (float*)(ws + (73ull << 20));

  conv_kernel<<<16384, 256, 0, stream>>>(x, xb, 1024, 1024);
  gate_kernel<<<4096, 64, 0, stream>>>(x, Wg, gw);

  for (int e = 0; e < 4; ++e) {
    const float* Wq = (const float*)d_in[2 + 8 * e + 0];
    const float* bq = (const float*)d_in[2 + 8 * e + 1];
    const float* Wk = (const float*)d_in[2 + 8 * e + 2];
    const float* bk = (const float*)d_in[2 + 8 * e + 3];
    const float* Wv = (const float*)d_in[2 + 8 * e + 4];
    const float* bv = (const float*)d_in[2 + 8 * e + 5];
    const float* Wo = (const float*)d_in[2 + 8 * e + 6];
    const float* bo = (const float*)d_in[2 + 8 * e + 7];
    int nh = nhs[e];
    int hd = H_ / nh;
    int pd = nh * hd;
    int ldqkv = (e == 1) ? 3456 : 3072;
    int qs_ncut = (e == 2) ? 0 : 1024;
    float qscale = LOG2E / sqrtf((float)hd);

    wtrans4_kernel<<<dim3(32, 32, 4), 256, 0, stream>>>(
        Wq, Wk, Wv, Wo, qkvT, qkvT + (1 << 20), qkvT + (2 << 20), woT, pd);

    gemm_mfma<<<dim3(24, 32), 256, 0, stream>>>(
        xb, qkvT, bq, bk, bv, qkv, ldqkv,
        (pd == 1020) ? 1020 : 1024, (e == 2) ? 2048 : 0, 1, 0, nullptr, 0,
        (e == 1) ? 1 : 0, qs_ncut, qscale);

    if (e == 2) {
      const unsigned short* qb = qkv;
      const unsigned short* kb = qkv + 1024;
      const unsigned short* vb = qkv + 2048;
      linkv_mfma<<<dim3(8, B_, NSPLIT), 256, 0, stream>>>(kb, vb, kvp, ksump, 3072);
      linkv_reduce<<<(32 * 128 * 128) / 256, 256, 0, stream>>>(kvp, ksump, kvb, ksum);
      linattn_mfma<<<dim3(S_ / 128, 8, B_), 256, 0, stream>>>(qb, kvb, ksum, aob, 3072);
    } else if (e == 1) {
      attn_mfma3<85, false><<<dim3(S_ / 256, 12, B_), 512, 0, stream>>>(
          qkv, qkv + 1152, qkv + 2304, amask, aob, 3456);
    } else if (e == 3) {
      attn_mfma3<128, true><<<dim3(S_ / 256, 8, B_), 512, 0, stream>>>(
          qkv, qkv + 1024, qkv + 2048, amask, aob, 3072);
    } else {
      attn_mfma3<128, false><<<dim3(S_ / 256, 8, B_), 512, 0, stream>>>(
          qkv, qkv + 1024, qkv + 2048, amask, aob, 3072);
    }

    gemm_mfma<<<dim3(8, 32), 256, 0, stream>>>(
        aob, woT, bo, bo, bo, out, 1024, 1024, 0, 0, (e == 0) ? 1 : 2, gw, e, 0,
        0, 1.0f);
  }
}

// Round 11
// 513.572 us; speedup vs baseline: 1.0940x; 1.0480x over previous
//
#include <hip/hip_runtime.h>
#include <cmath>

#define B_ 4
#define S_ 1024
#define H_ 1024

typedef short bf16x8 __attribute__((ext_vector_type(8)));
typedef float f32x4 __attribute__((ext_vector_type(4)));
typedef _Float16 half4 __attribute__((ext_vector_type(4)));

__device__ __forceinline__ unsigned short f2bf(float f) {
  unsigned u = __float_as_uint(f);
  u += 0x7fff + ((u >> 16) & 1);  // RTNE
  return (unsigned short)(u >> 16);
}
__device__ __forceinline__ float bf2f(unsigned short h) {
  return __uint_as_float(((unsigned)h) << 16);
}
__device__ __forceinline__ void gld16(const void* g, void* l) {
  __builtin_amdgcn_global_load_lds(
      (const __attribute__((address_space(1))) unsigned int*)g,
      (__attribute__((address_space(3))) unsigned int*)l, 16, 0, 0);
}

// ---------------------------------------------------------------- gating ----
__global__ __launch_bounds__(64) void gate_kernel(
    const float* __restrict__ x, const float* __restrict__ Wg,
    float* __restrict__ gw) {
  int t = blockIdx.x;
  int lane = threadIdx.x;
  const float* xr = x + (size_t)t * H_;
  float a0 = 0.f, a1 = 0.f, a2 = 0.f, a3 = 0.f;
  for (int h = lane; h < H_; h += 64) {
    float xv = xr[h];
    const float* wr = Wg + h * 4;
    a0 += xv * wr[0]; a1 += xv * wr[1]; a2 += xv * wr[2]; a3 += xv * wr[3];
  }
  for (int off = 32; off > 0; off >>= 1) {
    a0 += __shfl_down(a0, off);
    a1 += __shfl_down(a1, off);
    a2 += __shfl_down(a2, off);
    a3 += __shfl_down(a3, off);
  }
  if (lane == 0) {
    float v[4] = {a0, a1, a2, a3};
    int i0 = 0; float b0 = v[0];
    for (int e = 1; e < 4; ++e) if (v[e] > b0) { b0 = v[e]; i0 = e; }
    int i1 = -1; float b1 = -INFINITY;
    for (int e = 0; e < 4; ++e) { if (e == i0) continue; if (v[e] > b1) { b1 = v[e]; i1 = e; } }
    float e1v = expf(b1 - b0);
    float w0 = 1.f / (1.f + e1v);
    float w1 = e1v / (1.f + e1v);
    float o[4] = {0.f, 0.f, 0.f, 0.f};
    o[i0] = w0; o[i1] = w1;
    float* g = gw + t * 4;
    g[0] = o[0]; g[1] = o[1]; g[2] = o[2]; g[3] = o[3];
  }
}

// ---------------- gating + fp32->bf16 conversion fused (same math/order) ----
__global__ __launch_bounds__(64) void gate_conv_kernel(
    const float* __restrict__ x, const float* __restrict__ Wg,
    float* __restrict__ gw, unsigned short* __restrict__ xb) {
  int t = blockIdx.x;
  int lane = threadIdx.x;
  const float* xr = x + (size_t)t * H_;
  unsigned short* xbr = xb + (size_t)t * H_;
  float a0 = 0.f, a1 = 0.f, a2 = 0.f, a3 = 0.f;
  for (int h = lane; h < H_; h += 64) {
    float xv = xr[h];
    xbr[h] = f2bf(xv);
    const float* wr = Wg + h * 4;
    a0 += xv * wr[0]; a1 += xv * wr[1]; a2 += xv * wr[2]; a3 += xv * wr[3];
  }
  for (int off = 32; off > 0; off >>= 1) {
    a0 += __shfl_down(a0, off);
    a1 += __shfl_down(a1, off);
    a2 += __shfl_down(a2, off);
    a3 += __shfl_down(a3, off);
  }
  if (lane == 0) {
    float v[4] = {a0, a1, a2, a3};
    int i0 = 0; float b0 = v[0];
    for (int e = 1; e < 4; ++e) if (v[e] > b0) { b0 = v[e]; i0 = e; }
    int i1 = -1; float b1 = -INFINITY;
    for (int e = 0; e < 4; ++e) { if (e == i0) continue; if (v[e] > b1) { b1 = v[e]; i1 = e; } }
    float e1v = expf(b1 - b0);
    float w0 = 1.f / (1.f + e1v);
    float w1 = e1v / (1.f + e1v);
    float o[4] = {0.f, 0.f, 0.f, 0.f};
    o[i0] = w0; o[i1] = w1;
    float* g = gw + t * 4;
    g[0] = o[0]; g[1] = o[1]; g[2] = o[2]; g[3] = o[3];
  }
}

// -------------------------------------------------------- fp32 -> bf16 ------
__global__ __launch_bounds__(256) void conv_kernel(
    const float* __restrict__ src, unsigned short* __restrict__ dst,
    int nsrc, int ldsrc) {
  int idx = blockIdx.x * 256 + threadIdx.x;
  int m = idx >> 10, c = idx & 1023;
  dst[idx] = (c < nsrc) ? f2bf(src[(size_t)m * ldsrc + c]) : (unsigned short)0;
}

// --------------------- weight transpose + bf16, 4 matrices in one launch ----
__global__ __launch_bounds__(256) void wtrans4_kernel(
    const float* __restrict__ s0, const float* __restrict__ s1,
    const float* __restrict__ s2, const float* __restrict__ s3,
    unsigned short* __restrict__ d0, unsigned short* __restrict__ d1,
    unsigned short* __restrict__ d2, unsigned short* __restrict__ d3, int pd) {
  __shared__ float tile[32][33];
  int z = blockIdx.z;
  const float* src = (z == 0) ? s0 : (z == 1) ? s1 : (z == 2) ? s2 : s3;
  unsigned short* dst = (z == 0) ? d0 : (z == 1) ? d1 : (z == 2) ? d2 : d3;
  int ksrc = (z < 3) ? 1024 : pd;
  int nsrc = (z < 3) ? pd : 1024;
  int ldsrc = (z < 3) ? pd : 1024;
  int k0 = blockIdx.x * 32, n0 = blockIdx.y * 32;
  int tx = threadIdx.x & 31, ty = threadIdx.x >> 5;
  for (int i = 0; i < 32; i += 8) {
    int k = k0 + ty + i, n = n0 + tx;
    tile[ty + i][tx] = (k < ksrc && n < nsrc) ? src[(size_t)k * ldsrc + n] : 0.f;
  }
  __syncthreads();
  for (int i = 0; i < 32; i += 8) {
    int n = n0 + ty + i, k = k0 + tx;
    dst[(size_t)n * 1024 + k] = f2bf(tile[tx][ty + i]);
  }
}

// ------------- weight transpose, ALL 16 matrices (4 experts) in one launch --
struct W16 {
  const float* src[16];
  unsigned short* dst[16];
  int pd[4];
};
__global__ __launch_bounds__(256) void wtrans16_kernel(W16 p) {
  __shared__ float tile[32][33];
  int z = blockIdx.z;
  int e = z >> 2, m = z & 3;
  const float* src = p.src[z];
  unsigned short* dst = p.dst[z];
  int pd = p.pd[e];
  int ksrc = (m < 3) ? 1024 : pd;
  int nsrc = (m < 3) ? pd : 1024;
  int ldsrc = (m < 3) ? pd : 1024;
  int k0 = blockIdx.x * 32, n0 = blockIdx.y * 32;
  int tx = threadIdx.x & 31, ty = threadIdx.x >> 5;
  for (int i = 0; i < 32; i += 8) {
    int k = k0 + ty + i, n = n0 + tx;
    tile[ty + i][tx] = (k < ksrc && n < nsrc) ? src[(size_t)k * ldsrc + n] : 0.f;
  }
  __syncthreads();
  for (int i = 0; i < 32; i += 8) {
    int n = n0 + ty + i, k = k0 + tx;
    dst[(size_t)n * 1024 + k] = f2bf(tile[tx][ty + i]);
  }
}

// ------------------------------------------------------- bf16 MFMA GEMM -----
// (fallback path only; BK=32)
__global__ __launch_bounds__(256) void gemm_mfma(
    const unsigned short* __restrict__ A, const unsigned short* __restrict__ Bt,
    const float* __restrict__ b0, const float* __restrict__ b1,
    const float* __restrict__ b2, void* __restrict__ Cv, int ldc,
    int nact, int elu_ncut, int out_bf16, int mode,
    const float* __restrict__ gw, int expert, int remap,
    int qs_ncut, float qscale) {
  constexpr int K = 1024;
  __shared__ __align__(16) unsigned short As[128 * 32];
  __shared__ __align__(16) unsigned short Bs[128 * 32];
  int tid = threadIdx.x, wave = tid >> 6, lane = tid & 63;
  int quad = lane >> 4, lrow = lane & 15;
  int rw = (wave >> 1) * 64, cw = (wave & 1) * 64;
  int m0 = blockIdx.y * 128, n0 = blockIdx.x * 128;
  int srow = wave * 32 + (lane >> 2);
  int scol = (lane & 3) * 8;
  const unsigned short* gA = A + (size_t)(m0 + srow) * K + scol;
  const unsigned short* gB = Bt + (size_t)(n0 + srow) * K + scol;
  unsigned short* lA = &As[wave * 1024];
  unsigned short* lB = &Bs[wave * 1024];
  f32x4 acc[4][4];
#pragma unroll
  for (int mt = 0; mt < 4; ++mt)
#pragma unroll
    for (int nt = 0; nt < 4; ++nt) acc[mt][nt] = (f32x4){0.f, 0.f, 0.f, 0.f};

  for (int k0 = 0; k0 < K; k0 += 32) {
    gld16(gA + k0, lA);
    gld16(gA + 16 * K + k0, lA + 512);
    gld16(gB + k0, lB);
    gld16(gB + 16 * K + k0, lB + 512);
    __syncthreads();
    bf16x8 af[4], bfr[4];
#pragma unroll
    for (int t = 0; t < 4; ++t) {
      af[t]  = *(const bf16x8*)&As[(rw + t * 16 + lrow) * 32 + quad * 8];
      bfr[t] = *(const bf16x8*)&Bs[(cw + t * 16 + lrow) * 32 + quad * 8];
    }
#pragma unroll
    for (int mt = 0; mt < 4; ++mt)
#pragma unroll
      for (int nt = 0; nt < 4; ++nt)
        acc[mt][nt] = __builtin_amdgcn_mfma_f32_16x16x32_bf16(
            af[mt], bfr[nt], acc[mt][nt], 0, 0, 0);
    __syncthreads();
  }
#pragma unroll
  for (int nt = 0; nt < 4; ++nt) {
    int n = n0 + cw + nt * 16 + lrow;
    int slice = n >> 10, noff = n & 1023;
    if (noff >= nact) continue;
    const float* bp = (slice == 0) ? b0 : (slice == 1) ? b1 : b2;
    float bias = bp[noff];
    bool do_elu = n < elu_ncut;
    bool do_qs = n < qs_ncut;
    int col = n;
    if (remap) {
      int head = (noff * 12337) >> 20;  // noff/85 for noff<1020
      col = slice * 1152 + head * 96 + (noff - head * 85);
    }
#pragma unroll
    for (int mt = 0; mt < 4; ++mt) {
      int mb = m0 + rw + mt * 16 + quad * 4;
#pragma unroll
      for (int r = 0; r < 4; ++r) {
        int m = mb + r;
        float val = acc[mt][nt][r] + bias;
        if (do_elu) val = (val > 0.f) ? val + 1.f : expf(val);
        if (do_qs) val *= qscale;
        size_t ci = (size_t)m * ldc + col;
        if (out_bf16) {
          ((unsigned short*)Cv)[ci] = f2bf(val);
        } else {
          float* C = (float*)Cv;
          if (mode == 0) C[ci] = val;
          else {
            float g = gw[m * 4 + expert];
            if (mode == 1) C[ci] = g * val;
            else           C[ci] += g * val;
          }
        }
      }
    }
  }
}

// --------------------------- merged QKV projection GEMM, z=expert -----------
// R7's measured-best (159.7 µs): 128² tile, BK=64 as TWO BK=32 panels,
// 256 thr. Restored verbatim after 256² variants (R8/R9/R10) all measured
// slower on this shape.
struct QkvP {
  const unsigned short* Bt[4];
  const float* bq[4];
  const float* bk[4];
  const float* bv[4];
  unsigned short* C[4];
  int ldc[4];
  int nact[4];
  int elu_ncut[4];
  int remap[4];
  int qs_ncut[4];
  float qscale[4];
};
__global__ __launch_bounds__(256) void gemm_qkv4(
    const unsigned short* __restrict__ A, QkvP p) {
  constexpr int K = 1024;
  __shared__ __align__(16) unsigned short As[2 * 128 * 32];
  __shared__ __align__(16) unsigned short Bs[2 * 128 * 32];
  int e = blockIdx.z;
  const unsigned short* Bt = p.Bt[e];
  unsigned short* Cv = p.C[e];
  int ldc = p.ldc[e], nact = p.nact[e], elu_ncut = p.elu_ncut[e];
  int remap = p.remap[e], qs_ncut = p.qs_ncut[e];
  float qscale = p.qscale[e];
  int tid = threadIdx.x, wave = tid >> 6, lane = tid & 63;
  int quad = lane >> 4, lrow = lane & 15;
  int rw = (wave >> 1) * 64, cw = (wave & 1) * 64;
  int m0 = blockIdx.y * 128, n0 = blockIdx.x * 128;
  int srow = wave * 32 + (lane >> 2);
  int scol = (lane & 3) * 8;
  const unsigned short* gA = A + (size_t)(m0 + srow) * K + scol;
  const unsigned short* gB = Bt + (size_t)(n0 + srow) * K + scol;
  unsigned short* lA = &As[wave * 1024];
  unsigned short* lB = &Bs[wave * 1024];
  f32x4 acc[4][4];
#pragma unroll
  for (int mt = 0; mt < 4; ++mt)
#pragma unroll
    for (int nt = 0; nt < 4; ++nt) acc[mt][nt] = (f32x4){0.f, 0.f, 0.f, 0.f};

  for (int k0 = 0; k0 < K; k0 += 64) {
    gld16(gA + k0, lA);
    gld16(gA + 16 * K + k0, lA + 512);
    gld16(gA + k0 + 32, lA + 4096);
    gld16(gA + 16 * K + k0 + 32, lA + 4096 + 512);
    gld16(gB + k0, lB);
    gld16(gB + 16 * K + k0, lB + 512);
    gld16(gB + k0 + 32, lB + 4096);
    gld16(gB + 16 * K + k0 + 32, lB + 4096 + 512);
    __syncthreads();
#pragma unroll
    for (int kk = 0; kk < 2; ++kk) {
      const unsigned short* Ap = As + kk * 4096;
      const unsigned short* Bp = Bs + kk * 4096;
      bf16x8 af[4], bfr[4];
#pragma unroll
      for (int t = 0; t < 4; ++t) {
        af[t]  = *(const bf16x8*)&Ap[(rw + t * 16 + lrow) * 32 + quad * 8];
        bfr[t] = *(const bf16x8*)&Bp[(cw + t * 16 + lrow) * 32 + quad * 8];
      }
#pragma unroll
      for (int mt = 0; mt < 4; ++mt)
#pragma unroll
        for (int nt = 0; nt < 4; ++nt)
          acc[mt][nt] = __builtin_amdgcn_mfma_f32_16x16x32_bf16(
              af[mt], bfr[nt], acc[mt][nt], 0, 0, 0);
    }
    __syncthreads();
  }
#pragma unroll
  for (int nt = 0; nt < 4; ++nt) {
    int n = n0 + cw + nt * 16 + lrow;
    int slice = n >> 10, noff = n & 1023;
    if (noff >= nact) continue;
    const float* bp = (slice == 0) ? p.bq[e] : (slice == 1) ? p.bk[e] : p.bv[e];
    float bias = bp[noff];
    bool do_elu = n < elu_ncut;
    bool do_qs = n < qs_ncut;
    int col = n;
    if (remap) {
      int head = (noff * 12337) >> 20;  // noff/85 for noff<1020
      col = slice * 1152 + head * 96 + (noff - head * 85);
    }
#pragma unroll
    for (int mt = 0; mt < 4; ++mt) {
      int mb = m0 + rw + mt * 16 + quad * 4;
#pragma unroll
      for (int r = 0; r < 4; ++r) {
        int m = mb + r;
        float val = acc[mt][nt][r] + bias;
        if (do_elu) val = (val > 0.f) ? val + 1.f : expf(val);
        if (do_qs) val *= qscale;
        Cv[(size_t)m * ldc + col] = f2bf(val);
      }
    }
  }
}

// ==================== 256x256 8-phase GEMM core (R8's measured-best) ========
// Used ONLY for the output projection (N=1024 shape), where R8's cross-round
// delta showed it ~11 µs faster than the 128² version. Verbatim R8 core.
__device__ __forceinline__ void stage_half(
    const unsigned short* __restrict__ G, int grow0, int kbase,
    unsigned short* lhalf, int wave, int lane) {
#pragma unroll
  for (int j = 0; j < 2; ++j) {
    int t = j * 512 + wave * 64 + lane;     // 0..1023 16B-slot within half-tile
    int rl = t >> 3;                         // row 0..127 within half
    int cs = (t & 7) * 8;                    // LDS col (ushorts) of this slot
    int c0 = cs ^ (((rl >> 2) & 1) << 4);    // logical col that belongs there
    gld16(G + (size_t)(grow0 + rl) * 1024 + kbase + c0,
          lhalf + (size_t)(j * 512 + wave * 64) * 8);  // wave-uniform dest
  }
}

__device__ __forceinline__ void gemm256_core(
    const unsigned short* __restrict__ A, const unsigned short* __restrict__ Bt,
    int m0, int n0, unsigned short* As, unsigned short* Bs,
    f32x4 (&acc)[8][4]) {
  int tid = threadIdx.x;
  int wave = tid >> 6, lane = tid & 63;
  int quad = lane >> 4, l15 = lane & 15;
  int wr = wave >> 2, wc = wave & 3;
#pragma unroll
  for (int mr = 0; mr < 8; ++mr)
#pragma unroll
    for (int nr = 0; nr < 4; ++nr) acc[mr][nr] = (f32x4){0.f, 0.f, 0.f, 0.f};
  // prologue: stage K-tile 0 into buffer 0 (4 half-tiles)
  stage_half(A, m0, 0, As, wave, lane);
  stage_half(A, m0 + 128, 0, As + 8192, wave, lane);
  stage_half(Bt, n0, 0, Bs, wave, lane);
  stage_half(Bt, n0 + 128, 0, Bs + 8192, wave, lane);
  __syncthreads();
  int cur = 0;
  for (int t = 0; t < 16; ++t) {
    const unsigned short* Ar = As + cur * 16384;
    const unsigned short* Br = Bs + cur * 16384;
    unsigned short* Awr = As + (cur ^ 1) * 16384;
    unsigned short* Bwr = Bs + (cur ^ 1) * 16384;
    int kb = (t + 1) * 64;
    bool more = (t + 1 < 16);
    bf16x8 bfr[4];
#pragma unroll
    for (int p = 0; p < 4; ++p) {
      const int ks = p >> 1, mh = (p & 1) * 4;
      bf16x8 af[4];
#pragma unroll
      for (int i = 0; i < 4; ++i) {
        int row = wr * 128 + (mh + i) * 16 + l15;
        int c = ks * 32 + quad * 8;
        af[i] = *(const bf16x8*)&Ar[row * 64 + (c ^ (((row >> 2) & 1) << 4))];
      }
      if ((p & 1) == 0) {
#pragma unroll
        for (int i = 0; i < 4; ++i) {
          int row = wc * 64 + i * 16 + l15;
          int c = ks * 32 + quad * 8;
          bfr[i] = *(const bf16x8*)&Br[row * 64 + (c ^ (((row >> 2) & 1) << 4))];
        }
      }
      if (more) {  // stage one half-tile of tile t+1 into the other buffer
        if (p == 0) stage_half(A, m0, kb, Awr, wave, lane);
        else if (p == 1) stage_half(A, m0 + 128, kb, Awr + 8192, wave, lane);
        else if (p == 2) stage_half(Bt, n0, kb, Bwr, wave, lane);
        else stage_half(Bt, n0 + 128, kb, Bwr + 8192, wave, lane);
      }
      __builtin_amdgcn_s_barrier();
      __builtin_amdgcn_s_setprio(1);
#pragma unroll
      for (int i = 0; i < 4; ++i)
#pragma unroll
        for (int jn = 0; jn < 4; ++jn)
          acc[mh + i][jn] = __builtin_amdgcn_mfma_f32_16x16x32_bf16(
              af[i], bfr[jn], acc[mh + i][jn], 0, 0, 0);
      __builtin_amdgcn_s_setprio(0);
      __builtin_amdgcn_s_barrier();
    }
    __syncthreads();  // staged writes (vmcnt) complete + all readers done
    cur ^= 1;
  }
}

// ------------------------------------- merged output projection, z=expert ---
struct OutP {
  const unsigned short* A[4];
  const unsigned short* B[4];
  const float* bias[4];
};
__global__ __launch_bounds__(512, 1) void gemm_out4_v2(
    OutP p, const float* __restrict__ gw, float* __restrict__ part) {
  __shared__ __align__(16) unsigned short As[2 * 256 * 64];
  __shared__ __align__(16) unsigned short Bs[2 * 256 * 64];
  int e = blockIdx.z;
  int flat = blockIdx.y * 4 + blockIdx.x;  // 64 blocks, 64%8==0
  int swz = (flat & 7) * 8 + (flat >> 3);
  int m0 = (swz / 4) * 256, n0 = (swz % 4) * 256;
  f32x4 acc[8][4];
  gemm256_core(p.A[e], p.B[e], m0, n0, As, Bs, acc);
  const float* bp = p.bias[e];
  float* C = part + (size_t)e * (4096ull * 1024ull);
  int tid = threadIdx.x, wave = tid >> 6, lane = tid & 63;
  int quad = lane >> 4, l15 = lane & 15;
  int wr = wave >> 2, wc = wave & 3;
#pragma unroll
  for (int nr = 0; nr < 4; ++nr) {
    int n = n0 + wc * 64 + nr * 16 + l15;
    float bias = bp[n];
#pragma unroll
    for (int mr = 0; mr < 8; ++mr) {
      int mb = m0 + wr * 128 + mr * 16 + quad * 4;
#pragma unroll
      for (int r = 0; r < 4; ++r) {
        int m = mb + r;
        float g = gw[m * 4 + e];
        C[(size_t)m * 1024 + n] = g * (acc[mr][nr][r] + bias);
      }
    }
  }
}

// part[e] summed in expert order -> identical rounding to old mode1/mode2 chain
__global__ __launch_bounds__(256) void reduce4(
    const float* __restrict__ part, float* __restrict__ out) {
  constexpr size_t N = 4096ull * 1024ull;
  size_t idx = ((size_t)blockIdx.x * 256 + threadIdx.x) * 4;
  f32x4 a0 = *(const f32x4*)(part + idx);
  f32x4 a1 = *(const f32x4*)(part + idx + N);
  f32x4 a2 = *(const f32x4*)(part + idx + 2 * N);
  f32x4 a3 = *(const f32x4*)(part + idx + 3 * N);
  f32x4 s;
#pragma unroll
  for (int j = 0; j < 4; ++j) {
    float t = a0[j];
    t += a1[j]; t += a2[j]; t += a3[j];
    s[j] = t;
  }
  *(f32x4*)(out + idx) = s;
}

// ----- zero never-written pad columns (e1 head-pad 85..95, aob1 1020..1023) -
__global__ __launch_bounds__(256) void padzero(
    unsigned short* __restrict__ qkv1, unsigned short* __restrict__ aob1) {
  int idx = blockIdx.x * 256 + threadIdx.x;  // grid covers 4096*396 exactly
  int m = idx / 396, r = idx % 396;
  int slice = r / 132, r2 = r % 132;
  int head = r2 / 11, c = 85 + r2 % 11;
  qkv1[(size_t)m * 3456 + slice * 1152 + head * 96 + c] = 0;
  if (idx < 4096 * 4) {
    int mm = idx >> 2, cc = 1020 + (idx & 3);
    aob1[(size_t)mm * 1024 + cc] = 0;
  }
}

// --------------------------------------------- MFMA flash attention v6 ------
// 512 thr, QT=256, double-buffered Ks/Vt, one barrier per KT-iteration.
template <int HD, bool LOCAL>
__device__ __forceinline__ void attn_body(
    char* smem,
    const unsigned short* __restrict__ q, const unsigned short* __restrict__ k,
    const unsigned short* __restrict__ v, const int* __restrict__ amask,
    unsigned short* __restrict__ ao, int ldq, int h) {
  constexpr int HDP = (HD + 31) & ~31;  // 128 or 96
  constexpr int DCH = HDP / 32;         // 4 or 3
  constexpr int NDT = HDP / 16;         // 8 or 6
  constexpr int NCH = HDP / 8;          // 16 or 12
  constexpr int QT = 256, KT = 64;
  constexpr int KLD = HDP + 8;
  constexpr int VLD = KT + 4;
  constexpr int W2 = 32;
  constexpr int KSZ = KT * KLD;   // ushorts per K buffer
  constexpr int VSZ = HDP * VLD;  // halves per V buffer
  unsigned short* Ks = (unsigned short*)smem;              // [2][KSZ]
  _Float16* Vt = (_Float16*)(smem + 2 * KSZ * 2);          // [2][VSZ]
  unsigned long long* amq =
      (unsigned long long*)(smem + 2 * KSZ * 2 + 2 * VSZ * 2);
  int tid = threadIdx.x, wave = tid >> 6, lane = tid & 63;
  int quad = lane >> 4, l15 = lane & 15;
  int q0 = blockIdx.x * QT, b = blockIdx.z;
  size_t baseq = ((size_t)b * S_) * ldq + (size_t)h * HDP;
  size_t baseo = ((size_t)b * S_) * H_ + (size_t)h * HD;

  {
    unsigned long long bb0 = __ballot(amask[b * S_ + wave * 128 + lane] != 0);
    unsigned long long bb1 = __ballot(amask[b * S_ + wave * 128 + 64 + lane] != 0);
    if (lane == 0) { amq[wave * 2] = bb0; amq[wave * 2 + 1] = bb1; }
  }

  int qrow[2];
  bf16x8 qf[2][DCH];
#pragma unroll
  for (int g = 0; g < 2; ++g) {
    qrow[g] = q0 + wave * 32 + g * 16 + l15;
#pragma unroll
    for (int c = 0; c < DCH; ++c)
#pragma unroll
      for (int j = 0; j < 8; ++j) {
        int d = c * 32 + quad * 8 + j;
        qf[g][c][j] =
            (d < HD) ? (short)q[baseq + (size_t)qrow[g] * ldq + d] : (short)0;
      }
  }

  int jlo = 0, jhi = S_;
  if (LOCAL) {
    jlo = q0 - W2; if (jlo < 0) jlo = 0; jlo &= ~(KT - 1);
    jhi = q0 + QT + W2; if (jhi > S_) jhi = S_;
  }

  int skey = tid & 63, sc8a = tid >> 6, sc8b = 8 + (tid >> 6);
  bool sactb = sc8b < NCH;
  const unsigned short* kg = k + baseq + (size_t)skey * ldq;
  const unsigned short* vg = v + baseq + (size_t)skey * ldq;
  bf16x8 kra = {}, krb = {}, vra = {}, vrb = {};
  {
    size_t o = (size_t)jlo * ldq;
    kra = *(const bf16x8*)(kg + o + sc8a * 8);
    vra = *(const bf16x8*)(vg + o + sc8a * 8);
    if (sactb) {
      krb = *(const bf16x8*)(kg + o + sc8b * 8);
      vrb = *(const bf16x8*)(vg + o + sc8b * 8);
    }
  }

  // prologue: stage tile jlo into buffer 0
  {
    *(bf16x8*)&Ks[skey * KLD + sc8a * 8] = kra;
#pragma unroll
    for (int j = 0; j < 8; ++j)
      Vt[(sc8a * 8 + j) * VLD + skey] = (_Float16)bf2f((unsigned short)vra[j]);
    if (sactb) {
      *(bf16x8*)&Ks[skey * KLD + sc8b * 8] = krb;
#pragma unroll
      for (int j = 0; j < 8; ++j)
        Vt[(sc8b * 8 + j) * VLD + skey] = (_Float16)bf2f((unsigned short)vrb[j]);
    }
  }
  int cur = 0;
  __syncthreads();

  float m_run[2] = {-1e30f, -1e30f}, l_run[2] = {0.f, 0.f};
  f32x4 accd[2][NDT];
#pragma unroll
  for (int g = 0; g < 2; ++g)
#pragma unroll
    for (int dt = 0; dt < NDT; ++dt) accd[g][dt] = (f32x4){0.f, 0.f, 0.f, 0.f};

  for (int j0 = jlo; j0 < jhi; j0 += KT) {
    int jn = j0 + KT;
    if (jn < jhi) {
      size_t o = (size_t)jn * ldq;
      kra = *(const bf16x8*)(kg + o + sc8a * 8);
      vra = *(const bf16x8*)(vg + o + sc8a * 8);
      if (sactb) {
        krb = *(const bf16x8*)(kg + o + sc8b * 8);
        vrb = *(const bf16x8*)(vg + o + sc8b * 8);
      }
    }
    const unsigned short* KsR = Ks + cur * KSZ;
    const _Float16* VtR = Vt + cur * VSZ;
    f32x4 sf[2][4];
#pragma unroll
    for (int kt = 0; kt < 4; ++kt) {
      sf[0][kt] = (f32x4){0.f, 0.f, 0.f, 0.f};
      sf[1][kt] = (f32x4){0.f, 0.f, 0.f, 0.f};
#pragma unroll
      for (int c = 0; c < DCH; ++c) {
        bf16x8 kf = *(const bf16x8*)&KsR[(kt * 16 + l15) * KLD + c * 32 + quad * 8];
        sf[0][kt] = __builtin_amdgcn_mfma_f32_16x16x32_bf16(kf, qf[0][c], sf[0][kt], 0, 0, 0);
        sf[1][kt] = __builtin_amdgcn_mfma_f32_16x16x32_bf16(kf, qf[1][c], sf[1][kt], 0, 0, 0);
      }
    }
    unsigned long long mb = amq[j0 >> 6];
    unsigned mw[2] = {(unsigned)mb, (unsigned)(mb >> 32)};
    float pvv[2][4][4];
    float mx[2] = {-1e30f, -1e30f};
#pragma unroll
    for (int kt = 0; kt < 4; ++kt) {
      unsigned word = mw[kt >> 1];
      int sh = (kt & 1) * 16 + quad * 4;
#pragma unroll
      for (int r = 0; r < 4; ++r) {
        bool okm = (word >> (sh + r)) & 1;
#pragma unroll
        for (int g = 0; g < 2; ++g) {
          bool ok = okm;
          if (LOCAL) {
            int dj = (j0 + kt * 16 + quad * 4 + r) - qrow[g];
            ok = ok && (dj <= W2) && (dj >= -W2);
          }
          float s = ok ? sf[g][kt][r] : -1e30f;
          pvv[g][kt][r] = s;
          mx[g] = fmaxf(mx[g], s);
        }
      }
    }
    half4 pf[2][4];
    float aR[2][4];
#pragma unroll
    for (int g = 0; g < 2; ++g) {
      float mxg = fmaxf(mx[g], __shfl_xor(mx[g], 16));
      mxg = fmaxf(mxg, __shfl_xor(mxg, 32));
      float m_new = fmaxf(m_run[g], mxg);
      float psum = 0.f;
#pragma unroll
      for (int kt = 0; kt < 4; ++kt)
#pragma unroll
        for (int r = 0; r < 4; ++r) {
          float s = pvv[g][kt][r];
          float p = (s > -1e29f) ? __builtin_amdgcn_exp2f(s - m_new) : 0.f;
          pvv[g][kt][r] = p;
          psum += p;
        }
      psum += __shfl_xor(psum, 16);
      psum += __shfl_xor(psum, 32);
      float alpha = __builtin_amdgcn_exp2f(m_run[g] - m_new);
      m_run[g] = m_new;
      l_run[g] = l_run[g] * alpha + psum;
#pragma unroll
      for (int r = 0; r < 4; ++r)
        aR[g][r] = __shfl(alpha, (lane & 48) | (quad * 4 + r));
#pragma unroll
      for (int dt = 0; dt < NDT; ++dt)
#pragma unroll
        for (int r = 0; r < 4; ++r) accd[g][dt][r] *= aR[g][r];
#pragma unroll
      for (int kt = 0; kt < 4; ++kt)
#pragma unroll
        for (int r = 0; r < 4; ++r) pf[g][kt][r] = (_Float16)pvv[g][kt][r];
    }
    if (jn < jhi) {
      unsigned short* KsW = Ks + (cur ^ 1) * KSZ;
      _Float16* VtW = Vt + (cur ^ 1) * VSZ;
      *(bf16x8*)&KsW[skey * KLD + sc8a * 8] = kra;
#pragma unroll
      for (int j = 0; j < 8; ++j)
        VtW[(sc8a * 8 + j) * VLD + skey] = (_Float16)bf2f((unsigned short)vra[j]);
      if (sactb) {
        *(bf16x8*)&KsW[skey * KLD + sc8b * 8] = krb;
#pragma unroll
        for (int j = 0; j < 8; ++j)
          VtW[(sc8b * 8 + j) * VLD + skey] = (_Float16)bf2f((unsigned short)vrb[j]);
      }
    }
#pragma unroll
    for (int dt = 0; dt < NDT; ++dt)
#pragma unroll
      for (int kt = 0; kt < 4; ++kt) {
        half4 vf = *(const half4*)&VtR[(dt * 16 + l15) * VLD + kt * 16 + quad * 4];
        accd[0][dt] = __builtin_amdgcn_mfma_f32_16x16x16f16(pf[0][kt], vf, accd[0][dt], 0, 0, 0);
        accd[1][dt] = __builtin_amdgcn_mfma_f32_16x16x16f16(pf[1][kt], vf, accd[1][dt], 0, 0, 0);
      }
    __syncthreads();
    cur ^= 1;
  }
#pragma unroll
  for (int g = 0; g < 2; ++g) {
    float linv = (l_run[g] > 0.f) ? 1.f / l_run[g] : 0.f;
    float lR[4];
#pragma unroll
    for (int r = 0; r < 4; ++r)
      lR[r] = __shfl(linv, (lane & 48) | (quad * 4 + r));
#pragma unroll
    for (int dt = 0; dt < NDT; ++dt) {
      int d = dt * 16 + l15;
      if (d >= HD) continue;
#pragma unroll
      for (int r = 0; r < 4; ++r) {
        int row = q0 + wave * 32 + g * 16 + quad * 4 + r;
        ao[baseo + (size_t)row * H_ + d] = f2bf(accd[g][dt][r] * lR[r]);
      }
    }
  }
}

template <int HD, bool LOCAL>
__global__ __launch_bounds__(512) void attn_mfma3(
    const unsigned short* __restrict__ q, const unsigned short* __restrict__ k,
    const unsigned short* __restrict__ v, const int* __restrict__ amask,
    unsigned short* __restrict__ ao, int ldq) {
  constexpr int HDP = (HD + 31) & ~31;
  __shared__ __align__(16) char smem[2 * 64 * (HDP + 8) * 2 + 2 * HDP * 68 * 2 + 128];
  attn_body<HD, LOCAL>(smem, q, k, v, amask, ao, ldq, blockIdx.y);
}

// ------------------------------------------------------ linear attention ----
#define NSPLIT 4
__device__ __forceinline__ void linkv_body(
    char* smemi, const unsigned short* __restrict__ k,
    const unsigned short* __restrict__ v, float* __restrict__ kvp,
    float* __restrict__ ksump, int ld, int h, int b, int split, int tid) {
  constexpr int HD = 128;
  constexpr int TLD = 34;
  unsigned short* Kt = (unsigned short*)smemi;           // 8704 B
  unsigned short* Vt = Kt + HD * TLD;                    // 8704 B
  int bh = b * 8 + h;
  int wave = tid >> 6, lane = tid & 63;
  int quad = lane >> 4, l15 = lane & 15;
  int rw = (wave >> 1) * 64, cw = (wave & 1) * 64;
  size_t base = ((size_t)b * S_) * ld + (size_t)h * HD;
  int s_begin = split * (S_ / NSPLIT);

  f32x4 acc[4][4];
#pragma unroll
  for (int mt = 0; mt < 4; ++mt)
#pragma unroll
    for (int nt = 0; nt < 4; ++nt) acc[mt][nt] = (f32x4){0.f, 0.f, 0.f, 0.f};
  float ksacc = 0.f;
  int myd = tid & 127, half = tid >> 7;

  for (int c0 = 0; c0 < S_ / NSPLIT; c0 += 32) {
    for (int idx = tid; idx < 32 * HD; idx += 256) {
      int d = idx & 127, s = idx >> 7;
      size_t g = base + (size_t)(s_begin + c0 + s) * ld + d;
      Kt[d * TLD + s] = k[g];
      Vt[d * TLD + s] = v[g];
    }
    __syncthreads();
    bf16x8 af[4], bf[4];
#pragma unroll
    for (int t = 0; t < 4; ++t) {
      af[t] = *(const bf16x8*)&Vt[(rw + t * 16 + l15) * TLD + quad * 8];
      bf[t] = *(const bf16x8*)&Kt[(cw + t * 16 + l15) * TLD + quad * 8];
    }
#pragma unroll
    for (int mt = 0; mt < 4; ++mt)
#pragma unroll
      for (int nt = 0; nt < 4; ++nt)
        acc[mt][nt] = __builtin_amdgcn_mfma_f32_16x16x32_bf16(
            af[mt], bf[nt], acc[mt][nt], 0, 0, 0);
#pragma unroll
    for (int s = 0; s < 16; ++s)
      ksacc += bf2f(Kt[myd * TLD + half * 16 + s]);
    __syncthreads();
  }
  float* red = (float*)Kt;
  if (half == 1) red[myd] = ksacc;
  __syncthreads();
  if (half == 0)
    ksump[((size_t)split * 32 + bh) * HD + myd] = ksacc + red[myd];
  float* kvo = kvp + ((size_t)split * 32 + bh) * (HD * HD);
#pragma unroll
  for (int mt = 0; mt < 4; ++mt)
#pragma unroll
    for (int nt = 0; nt < 4; ++nt) {
      int dk = cw + nt * 16 + l15;
#pragma unroll
      for (int r = 0; r < 4; ++r) {
        int dv = rw + mt * 16 + quad * 4 + r;
        kvo[(size_t)dv * HD + dk] = acc[mt][nt][r];
      }
    }
}

__global__ __launch_bounds__(256) void linkv_mfma(
    const unsigned short* __restrict__ k, const unsigned short* __restrict__ v,
    float* __restrict__ kvp, float* __restrict__ ksump, int ld) {
  __shared__ __align__(16) char smemi[17408];
  linkv_body(smemi, k, v, kvp, ksump, ld, blockIdx.x, blockIdx.y, blockIdx.z,
             threadIdx.x);
}

// one launch: e0 (y<8) + e1 (y<20) + e3 local (y<28) + linkv e2 (y<32,
// two 256-thr instances per block). Grid (4, 32, 4) = 512 blocks = 2/CU.
__global__ __launch_bounds__(512) void attn_mega(
    const unsigned short* __restrict__ qkv0,
    const unsigned short* __restrict__ qkv1,
    const unsigned short* __restrict__ qkv2,
    const unsigned short* __restrict__ qkv3, const int* __restrict__ amask,
    unsigned short* __restrict__ ao0, unsigned short* __restrict__ ao1,
    unsigned short* __restrict__ ao3,
    float* __restrict__ kvp, float* __restrict__ ksump) {
  __shared__ __align__(16) char smem[69760];
  int y = blockIdx.y;
  if (y < 8)
    attn_body<128, false>(smem, qkv0, qkv0 + 1024, qkv0 + 2048, amask, ao0,
                          3072, y);
  else if (y < 20)
    attn_body<85, false>(smem, qkv1, qkv1 + 1152, qkv1 + 2304, amask, ao1,
                         3456, y - 8);
  else if (y < 28)
    attn_body<128, true>(smem, qkv3, qkv3 + 1024, qkv3 + 2048, amask, ao3,
                         3072, y - 20);
  else {
    int sub = threadIdx.x >> 8, stid = threadIdx.x & 255;
    int idx = (y - 28) * 8 + blockIdx.x * 2 + sub;  // 32 combos per b
    linkv_body(smem + sub * 17408, qkv2 + 1024, qkv2 + 2048, kvp, ksump, 3072,
               idx & 7, blockIdx.z, idx >> 3, stid);
  }
}

__global__ __launch_bounds__(256) void linkv_reduce(
    const float* __restrict__ kvp, const float* __restrict__ ksump,
    unsigned short* __restrict__ kvb, float* __restrict__ ksum) {
  int idx = blockIdx.x * 256 + threadIdx.x;
  float s = 0.f;
#pragma unroll
  for (int p = 0; p < NSPLIT; ++p) s += kvp[(size_t)p * (32 * 128 * 128) + idx];
  kvb[idx] = f2bf(s);
  if (idx < 32 * 128) {
    float t = 0.f;
#pragma unroll
    for (int p = 0; p < NSPLIT; ++p) t += ksump[(size_t)p * (32 * 128) + idx];
    ksum[idx] = t;
  }
}

__global__ __launch_bounds__(256) void linattn_mfma(
    const unsigned short* __restrict__ q, const unsigned short* __restrict__ kvT,
    const float* __restrict__ ksum, unsigned short* __restrict__ ao, int ldq) {
  constexpr int KLD = 136;
  __shared__ __align__(16) unsigned short Ks[128 * KLD];
  __shared__ float ksL[128];
  int tid = threadIdx.x, wave = tid >> 6, lane = tid & 63;
  int quad = lane >> 4, l15 = lane & 15;
  int rw = (wave >> 1) * 64, cw = (wave & 1) * 64;
  int q0 = blockIdx.x * 128, h = blockIdx.y, b = blockIdx.z;
  int bh = b * 8 + h;
  size_t baseq = ((size_t)b * S_) * ldq + (size_t)h * 128;
  size_t baseo = ((size_t)b * S_) * H_ + (size_t)h * 128;
  const unsigned short* kvg = kvT + (size_t)bh * (128 * 128);
  for (int idx = tid; idx < 128 * 16; idx += 256) {
    int e = idx >> 4, c = idx & 15;
    *(bf16x8*)&Ks[e * KLD + c * 8] = *(const bf16x8*)&kvg[e * 128 + c * 8];
  }
  if (tid < 128) ksL[tid] = ksum[(size_t)bh * 128 + tid];
  bf16x8 qf[4][4];
#pragma unroll
  for (int mt = 0; mt < 4; ++mt) {
    const unsigned short* qr = q + baseq + (size_t)(q0 + rw + mt * 16 + l15) * ldq;
#pragma unroll
    for (int kc = 0; kc < 4; ++kc)
      qf[mt][kc] = *(const bf16x8*)&qr[kc * 32 + quad * 8];
  }
  __syncthreads();
  f32x4 acc[4][4];
#pragma unroll
  for (int mt = 0; mt < 4; ++mt)
#pragma unroll
    for (int nt = 0; nt < 4; ++nt) acc[mt][nt] = (f32x4){0.f, 0.f, 0.f, 0.f};
#pragma unroll
  for (int kc = 0; kc < 4; ++kc) {
    bf16x8 bf[4];
#pragma unroll
    for (int nt = 0; nt < 4; ++nt)
      bf[nt] = *(const bf16x8*)&Ks[(cw + nt * 16 + l15) * KLD + kc * 32 + quad * 8];
#pragma unroll
    for (int mt = 0; mt < 4; ++mt)
#pragma unroll
      for (int nt = 0; nt < 4; ++nt)
        acc[mt][nt] = __builtin_amdgcn_mfma_f32_16x16x32_bf16(
            qf[mt][kc], bf[nt], acc[mt][nt], 0, 0, 0);
  }
  float den[4];
#pragma unroll
  for (int mt = 0; mt < 4; ++mt) {
    float s = 0.f;
#pragma unroll
    for (int kc = 0; kc < 4; ++kc)
#pragma unroll
      for (int j = 0; j < 8; ++j)
        s += bf2f((unsigned short)qf[mt][kc][j]) * ksL[kc * 32 + quad * 8 + j];
    s += __shfl_xor(s, 16);
    s += __shfl_xor(s, 32);
    den[mt] = s;
  }
#pragma unroll
  for (int mt = 0; mt < 4; ++mt)
#pragma unroll
    for (int r = 0; r < 4; ++r) {
      float dv = __shfl(den[mt], (lane & 48) | (quad * 4 + r));
      float inv = 1.f / (dv + 1e-6f);
      int row = q0 + rw + mt * 16 + quad * 4 + r;
#pragma unroll
      for (int nt = 0; nt < 4; ++nt) {
        int col = cw + nt * 16 + l15;
        ao[baseo + (size_t)row * H_ + col] = f2bf(acc[mt][nt][r] * inv);
      }
    }
}

// ---------------------------------------------------------------- launch ----
extern "C" void kernel_launch(void* const* d_in, const int* in_sizes, int n_in,
                              void* d_out, int out_size, void* d_ws, size_t ws_size,
                              hipStream_t stream) {
  const float* x = (const float*)d_in[0];
  const float* Wg = (const float*)d_in[1];
  const int* amask = (const int*)d_in[34];
  float* out = (float*)d_out;
  char* ws = (char*)d_ws;
  const size_t MiB = 1ull << 20;
  const int nhs[4] = {8, 12, 8, 8};
  const float LOG2E = 1.4426950408889634f;

  if (ws_size >= 157 * MiB) {
    // ---- merged schedule. Aliasing plan (stream-ordered live ranges):
    //   kvp    @ 4 MiB  (8 MiB)  over xb     — xb dead after gemm_qkv4;
    //          attn_mega's linkv instances write kvp (after gemm_qkv4 ✓)
    //   ksump  @ 12 MiB (64 KB)
    //   qkvT4  @ 125 MiB (24 MiB) over aobE[0..2] — dead after gemm_qkv4;
    //          padzero runs AFTER gemm_qkv4; attn rewrites aobE afterwards.
    //   part   @ 26 MiB (64 MiB) over qkvE[0..2] — dead after attn/linattn.
    float* gw = (float*)ws;                                  // 64 KB
    float* ksum = (float*)(ws + (64ull << 10));              // 16 KB
    unsigned short* kvb = (unsigned short*)(ws + 1 * MiB);   // 1 MiB
    unsigned short* xb = (unsigned short*)(ws + 4 * MiB);    // 8 MiB
    float* kvp = (float*)(ws + 4 * MiB);                     // 8 MiB (alias xb)
    float* ksump = (float*)(ws + 12 * MiB);                  // 64 KB
    unsigned short* woT[4];
    for (int e = 0; e < 4; ++e)
      woT[e] = (unsigned short*)(ws + (18 + 2 * e) * MiB);   // 8 MiB
    const size_t qkvOff[4] = {26 * MiB, 50 * MiB, 77 * MiB, 101 * MiB};
    unsigned short* qkvE[4];
    for (int e = 0; e < 4; ++e) qkvE[e] = (unsigned short*)(ws + qkvOff[e]);
    float* part = (float*)(ws + 26 * MiB);                   // 64 MiB (alias qkvE)
    unsigned short* aobE[4];
    for (int e = 0; e < 4; ++e)
      aobE[e] = (unsigned short*)(ws + (125 + 8 * e) * MiB); // 32 MiB total
    unsigned short* qkvT4 = (unsigned short*)(ws + 125 * MiB); // 24 MiB (alias)

    gate_conv_kernel<<<4096, 64, 0, stream>>>(x, Wg, gw, xb);

    // all 16 weight transposes in one launch
    W16 w;
    for (int e = 0; e < 4; ++e) {
      w.pd[e] = nhs[e] * (H_ / nhs[e]);
      for (int m = 0; m < 3; ++m) {
        w.src[e * 4 + m] = (const float*)d_in[2 + 8 * e + 2 * m];  // Wq,Wk,Wv
        w.dst[e * 4 + m] = qkvT4 + (size_t)(e * 3 + m) * (1 << 20);
      }
      w.src[e * 4 + 3] = (const float*)d_in[2 + 8 * e + 6];        // Wo
      w.dst[e * 4 + 3] = woT[e];
    }
    wtrans16_kernel<<<dim3(32, 32, 16), 256, 0, stream>>>(w);

    // all 4 QKV projections in one launch (R7's 128² BK=64 — measured best)
    QkvP qp;
    for (int e = 0; e < 4; ++e) {
      int hd = H_ / nhs[e];
      int pd = nhs[e] * hd;
      qp.Bt[e] = qkvT4 + (size_t)(e * 3) * (1 << 20);
      qp.bq[e] = (const float*)d_in[2 + 8 * e + 1];
      qp.bk[e] = (const float*)d_in[2 + 8 * e + 3];
      qp.bv[e] = (const float*)d_in[2 + 8 * e + 5];
      qp.C[e] = qkvE[e];
      qp.ldc[e] = (e == 1) ? 3456 : 3072;
      qp.nact[e] = (pd == 1020) ? 1020 : 1024;
      qp.elu_ncut[e] = (e == 2) ? 2048 : 0;
      qp.remap[e] = (e == 1) ? 1 : 0;
      qp.qs_ncut[e] = (e == 2) ? 0 : 1024;
      qp.qscale[e] = LOG2E / sqrtf((float)hd);
    }
    gemm_qkv4<<<dim3(24, 32, 4), 256, 0, stream>>>(xb, qp);

    // zero pad cols AFTER qkvT4 (aliasing aobE) is dead
    padzero<<<6336, 256, 0, stream>>>(qkvE[1], aobE[1]);

    // merged attention + linkv (kvp clobbers xb — dead now)
    attn_mega<<<dim3(S_ / 256, 32, B_), 512, 0, stream>>>(
        qkvE[0], qkvE[1], qkvE[2], qkvE[3], amask, aobE[0], aobE[1], aobE[3],
        kvp, ksump);

    linkv_reduce<<<(32 * 128 * 128) / 256, 256, 0, stream>>>(kvp, ksump, kvb, ksum);
    linattn_mfma<<<dim3(S_ / 128, 8, B_), 256, 0, stream>>>(
        qkvE[2], kvb, ksum, aobE[2], 3072);

    OutP p;
    for (int e = 0; e < 4; ++e) {
      p.A[e] = aobE[e];
      p.B[e] = woT[e];
      p.bias[e] = (const float*)d_in[2 + 8 * e + 7];
    }
    gemm_out4_v2<<<dim3(4, 16, 4), 512, 0, stream>>>(p, gw, part);
    reduce4<<<4096, 256, 0, stream>>>(part, out);
    return;
  }

  // ---- fallback: original sequential schedule (74 MiB workspace) ----
  float* gw            = (float*)(ws + 0);
  unsigned short* kvb  = (unsigned short*)(ws + (1ull << 20));
  float* ksum          = (float*)(ws + (3ull << 20) + (1ull << 19));
  unsigned short* xb   = (unsigned short*)(ws + (4ull << 20));
  unsigned short* qkvT = (unsigned short*)(ws + (12ull << 20));
  unsigned short* woT  = (unsigned short*)(ws + (18ull << 20));
  unsigned short* qkv  = (unsigned short*)(ws + (20ull << 20));
  unsigned short* aob  = (unsigned short*)(ws + (49ull << 20));
  float* kvp           = (float*)(ws + (57ull << 20));
  float* ksump         = (float*)(ws + (73ull << 20));

  conv_kernel<<<16384, 256, 0, stream>>>(x, xb, 1024, 1024);
  gate_kernel<<<4096, 64, 0, stream>>>(x, Wg, gw);

  for (int e = 0; e < 4; ++e) {
    const float* Wq = (const float*)d_in[2 + 8 * e + 0];
    const float* bq = (const float*)d_in[2 + 8 * e + 1];
    const float* Wk = (const float*)d_in[2 + 8 * e + 2];
    const float* bk = (const float*)d_in[2 + 8 * e + 3];
    const float* Wv = (const float*)d_in[2 + 8 * e + 4];
    const float* bv = (const float*)d_in[2 + 8 * e + 5];
    const float* Wo = (const float*)d_in[2 + 8 * e + 6];
    const float* bo = (const float*)d_in[2 + 8 * e + 7];
    int nh = nhs[e];
    int hd = H_ / nh;
    int pd = nh * hd;
    int ldqkv = (e == 1) ? 3456 : 3072;
    int qs_ncut = (e == 2) ? 0 : 1024;
    float qscale = LOG2E / sqrtf((float)hd);

    wtrans4_kernel<<<dim3(32, 32, 4), 256, 0, stream>>>(
        Wq, Wk, Wv, Wo, qkvT, qkvT + (1 << 20), qkvT + (2 << 20), woT, pd);

    gemm_mfma<<<dim3(24, 32), 256, 0, stream>>>(
        xb, qkvT, bq, bk, bv, qkv, ldqkv,
        (pd == 1020) ? 1020 : 1024, (e == 2) ? 2048 : 0, 1, 0, nullptr, 0,
        (e == 1) ? 1 : 0, qs_ncut, qscale);

    if (e == 2) {
      const unsigned short* qb = qkv;
      const unsigned short* kb = qkv + 1024;
      const unsigned short* vb = qkv + 2048;
      linkv_mfma<<<dim3(8, B_, NSPLIT), 256, 0, stream>>>(kb, vb, kvp, ksump, 3072);
      linkv_reduce<<<(32 * 128 * 128) / 256, 256, 0, stream>>>(kvp, ksump, kvb, ksum);
      linattn_mfma<<<dim3(S_ / 128, 8, B_), 256, 0, stream>>>(qb, kvb, ksum, aob, 3072);
    } else if (e == 1) {
      attn_mfma3<85, false><<<dim3(S_ / 256, 12, B_), 512, 0, stream>>>(
          qkv, qkv + 1152, qkv + 2304, amask, aob, 3456);
    } else if (e == 3) {
      attn_mfma3<128, true><<<dim3(S_ / 256, 8, B_), 512, 0, stream>>>(
          qkv, qkv + 1024, qkv + 2048, amask, aob, 3072);
    } else {
      attn_mfma3<128, false><<<dim3(S_ / 256, 8, B_), 512, 0, stream>>>(
          qkv, qkv + 1024, qkv + 2048, amask, aob, 3072);
    }

    gemm_mfma<<<dim3(8, 32), 256, 0, stream>>>(
        aob, woT, bo, bo, bo, out, 1024, 1024, 0, 0, (e == 0) ? 1 : 2, gw, e, 0,
        0, 1.0f);
  }
}